// Round 1
// baseline (1363.185 us; speedup 1.0000x reference)
//
#include <hip/hip_runtime.h>
#include <hip/hip_bf16.h>

#define HIDDEN 1024
#define NHEAD 16
#define HDIM 64
#define VOCAB 32000
#define SEQLEN 1024
#define EMBED 512
#define BATCH 4
#define ROWS (BATCH*SEQLEN)   // 4096

typedef __bf16 bf16x8 __attribute__((ext_vector_type(8)));
typedef float f32x4 __attribute__((ext_vector_type(4)));

__device__ __forceinline__ unsigned short f2bf(float f) {
  unsigned u = __builtin_bit_cast(unsigned, f);
  u = u + 0x7FFFu + ((u >> 16) & 1u);
  return (unsigned short)(u >> 16);
}

// ---------------- embedding: h0[row][e] = W_word[ids[row]][e] + W_pos[row%1024][e]
__global__ void embed_kernel(const int* __restrict__ ids,
                             const float* __restrict__ W_word,
                             const float* __restrict__ W_pos,
                             float* __restrict__ out) {
  int row = blockIdx.x;             // 0..4095
  int s = row & (SEQLEN - 1);
  int id = ids[row];
  int e = threadIdx.x * 4;
  float4 a = *(const float4*)(W_word + (size_t)id * EMBED + e);
  float4 b = *(const float4*)(W_pos + (size_t)s * EMBED + e);
  float4 o; o.x = a.x + b.x; o.y = a.y + b.y; o.z = a.z + b.z; o.w = a.w + b.w;
  *(float4*)(out + (size_t)row * EMBED + e) = o;
}

// ---------------- GEMM: C[m,n] = sum_k A[m,k] * B[n,k]  (+epilogue)
// A: [M,K] f32 row-major.  B: [N,K] f32 row-major (i.e. W with y = x @ W.T).
// EPI: 0 = none, 1 = += R (R same layout/ld as C; may alias C), 2 = relu.
#define BM 128
#define BN 128
#define BK 64
#define LSTR 72   // padded LDS row stride (bf16 elems): 144 B, breaks bank conflicts

template<int EPI>
__global__ __launch_bounds__(256) void gemm_bt(const float* __restrict__ A,
                                               const float* __restrict__ B,
                                               float* __restrict__ C,
                                               const float* __restrict__ R,
                                               int K, int ldc) {
  __shared__ unsigned short Asm[BM * LSTR];
  __shared__ unsigned short Bsm[BN * LSTR];
  int tid = threadIdx.x;
  int lane = tid & 63, wave = tid >> 6;
  int wr = wave >> 1, wc = wave & 1;
  int cl = lane & 15, gp = lane >> 4;
  int m0 = blockIdx.x * BM;
  int n0 = blockIdx.y * BN;

  f32x4 acc[4][4] = {};
  int nk = K / BK;
  for (int kt = 0; kt < nk; ++kt) {
    int kb = kt * BK;
    #pragma unroll
    for (int it = 0; it < 8; ++it) {
      int idx = it * 256 + tid;
      int row = idx >> 4;
      int c4 = (idx & 15) * 4;
      float4 av = *(const float4*)(A + (size_t)(m0 + row) * K + kb + c4);
      float4 bv = *(const float4*)(B + (size_t)(n0 + row) * K + kb + c4);
      unsigned a01 = f2bf(av.x) | ((unsigned)f2bf(av.y) << 16);
      unsigned a23 = f2bf(av.z) | ((unsigned)f2bf(av.w) << 16);
      unsigned b01 = f2bf(bv.x) | ((unsigned)f2bf(bv.y) << 16);
      unsigned b23 = f2bf(bv.z) | ((unsigned)f2bf(bv.w) << 16);
      *(uint2*)&Asm[row * LSTR + c4] = make_uint2(a01, a23);
      *(uint2*)&Bsm[row * LSTR + c4] = make_uint2(b01, b23);
    }
    __syncthreads();
    #pragma unroll
    for (int ks = 0; ks < 2; ++ks) {
      int ko = ks * 32 + gp * 8;
      bf16x8 af[4], bfv[4];
      #pragma unroll
      for (int m = 0; m < 4; ++m)
        af[m] = *(const bf16x8*)&Asm[(wr * 64 + m * 16 + cl) * LSTR + ko];
      #pragma unroll
      for (int n = 0; n < 4; ++n)
        bfv[n] = *(const bf16x8*)&Bsm[(wc * 64 + n * 16 + cl) * LSTR + ko];
      #pragma unroll
      for (int m = 0; m < 4; ++m)
        #pragma unroll
        for (int n = 0; n < 4; ++n)
          acc[m][n] = __builtin_amdgcn_mfma_f32_16x16x32_bf16(af[m], bfv[n], acc[m][n], 0, 0, 0);
    }
    __syncthreads();
  }
  // epilogue: C/D layout col = lane&15, row = (lane>>4)*4 + j
  int r0 = gp * 4;
  #pragma unroll
  for (int m = 0; m < 4; ++m) {
    #pragma unroll
    for (int n = 0; n < 4; ++n) {
      int col = n0 + wc * 64 + n * 16 + cl;
      #pragma unroll
      for (int j = 0; j < 4; ++j) {
        int row = m0 + wr * 64 + m * 16 + r0 + j;
        float v = acc[m][n][j];
        if (EPI == 1) v += R[(size_t)row * ldc + col];
        if (EPI == 2) v = fmaxf(v, 0.f);
        C[(size_t)row * ldc + col] = v;
      }
    }
  }
}

// ---------------- fused causal attention (flash-style)
// qkv: [B*S, 3*HIDDEN] f32; out: [B*S, HIDDEN] f32
// block = (qb 0..15, head 0..15, batch 0..3), 256 threads = 4 waves x 16 q-rows
__global__ __launch_bounds__(256) void attn_kernel(const float* __restrict__ qkv,
                                                   float* __restrict__ out) {
  __shared__ unsigned short Ksm[64 * LSTR];
  __shared__ unsigned short Vsm[64 * LSTR];   // transposed: [d][k]
  __shared__ unsigned short Psm[64 * LSTR];
  int qb = blockIdx.x, h = blockIdx.y, b = blockIdx.z;
  int tid = threadIdx.x;
  int lane = tid & 63, wave = tid >> 6;
  int cl = lane & 15, gp = lane >> 4;

  const float* base = qkv + (size_t)b * SEQLEN * (3 * HIDDEN);

  // Q fragments (A-operand rows = wave*16 + cl)
  int qrow_a = qb * 64 + wave * 16 + cl;
  bf16x8 qf[2];
  {
    const float* qp = base + (size_t)qrow_a * (3 * HIDDEN) + h * HDIM;
    #pragma unroll
    for (int st = 0; st < 2; ++st) {
      int d0 = st * 32 + gp * 8;
      float4 v0 = *(const float4*)(qp + d0);
      float4 v1 = *(const float4*)(qp + d0 + 4);
      union { bf16x8 v; unsigned short s[8]; } u;
      u.s[0] = f2bf(v0.x); u.s[1] = f2bf(v0.y); u.s[2] = f2bf(v0.z); u.s[3] = f2bf(v0.w);
      u.s[4] = f2bf(v1.x); u.s[5] = f2bf(v1.y); u.s[6] = f2bf(v1.z); u.s[7] = f2bf(v1.w);
      qf[st] = u.v;
    }
  }

  float mrow[4], lrow[4];
  f32x4 oacc[4] = {};
  #pragma unroll
  for (int j = 0; j < 4; ++j) { mrow[j] = -INFINITY; lrow[j] = 0.f; }

  for (int t = 0; t <= qb; ++t) {
    // stage K tile [64][64] and V^T tile [64 d][64 k]
    #pragma unroll
    for (int it = 0; it < 4; ++it) {
      int idx = it * 256 + tid;
      int row = idx >> 4;          // kv row 0..63
      int c4 = (idx & 15) * 4;     // d
      const float* kp = base + (size_t)(t * 64 + row) * (3 * HIDDEN) + HIDDEN + h * HDIM + c4;
      const float* vp = base + (size_t)(t * 64 + row) * (3 * HIDDEN) + 2 * HIDDEN + h * HDIM + c4;
      float4 k4 = *(const float4*)kp;
      float4 v4 = *(const float4*)vp;
      unsigned k01 = f2bf(k4.x) | ((unsigned)f2bf(k4.y) << 16);
      unsigned k23 = f2bf(k4.z) | ((unsigned)f2bf(k4.w) << 16);
      *(uint2*)&Ksm[row * LSTR + c4] = make_uint2(k01, k23);
      Vsm[(c4 + 0) * LSTR + row] = f2bf(v4.x);
      Vsm[(c4 + 1) * LSTR + row] = f2bf(v4.y);
      Vsm[(c4 + 2) * LSTR + row] = f2bf(v4.z);
      Vsm[(c4 + 3) * LSTR + row] = f2bf(v4.w);
    }
    __syncthreads();

    // S = Q K^T * (1/32)
    f32x4 sfr[4];
    #pragma unroll
    for (int n = 0; n < 4; ++n) {
      f32x4 z = {};
      #pragma unroll
      for (int ks = 0; ks < 2; ++ks) {
        int ko = ks * 32 + gp * 8;
        bf16x8 kf = *(const bf16x8*)&Ksm[(n * 16 + cl) * LSTR + ko];
        z = __builtin_amdgcn_mfma_f32_16x16x32_bf16(qf[ks], kf, z, 0, 0, 0);
      }
      sfr[n] = z;
    }
    // mask + scale
    #pragma unroll
    for (int n = 0; n < 4; ++n)
      #pragma unroll
      for (int j = 0; j < 4; ++j) {
        int qg = qb * 64 + wave * 16 + gp * 4 + j;
        int kg = t * 64 + n * 16 + cl;
        float sv = sfr[n][j] * 0.03125f;
        sfr[n][j] = (kg <= qg) ? sv : -1e30f;
      }
    // online softmax (rows live in 16-lane groups)
    float so[4];
    #pragma unroll
    for (int j = 0; j < 4; ++j) {
      float tm = fmaxf(fmaxf(sfr[0][j], sfr[1][j]), fmaxf(sfr[2][j], sfr[3][j]));
      tm = fmaxf(tm, __shfl_xor(tm, 1));
      tm = fmaxf(tm, __shfl_xor(tm, 2));
      tm = fmaxf(tm, __shfl_xor(tm, 4));
      tm = fmaxf(tm, __shfl_xor(tm, 8));
      float mn = fmaxf(mrow[j], tm);
      so[j] = expf(mrow[j] - mn);
      mrow[j] = mn;
      float ts = 0.f;
      #pragma unroll
      for (int n = 0; n < 4; ++n) {
        float p = expf(sfr[n][j] - mn);
        sfr[n][j] = p;
        ts += p;
      }
      ts += __shfl_xor(ts, 1); ts += __shfl_xor(ts, 2);
      ts += __shfl_xor(ts, 4); ts += __shfl_xor(ts, 8);
      lrow[j] = lrow[j] * so[j] + ts;
    }
    #pragma unroll
    for (int n = 0; n < 4; ++n)
      #pragma unroll
      for (int j = 0; j < 4; ++j)
        oacc[n][j] *= so[j];
    // P -> LDS (bf16), per-wave region
    #pragma unroll
    for (int n = 0; n < 4; ++n)
      #pragma unroll
      for (int j = 0; j < 4; ++j)
        Psm[(wave * 16 + gp * 4 + j) * LSTR + n * 16 + cl] = f2bf(sfr[n][j]);
    // O += P V
    #pragma unroll
    for (int n = 0; n < 4; ++n) {
      #pragma unroll
      for (int ks = 0; ks < 2; ++ks) {
        int ko = ks * 32 + gp * 8;
        bf16x8 pa = *(const bf16x8*)&Psm[(wave * 16 + cl) * LSTR + ko];
        bf16x8 vb = *(const bf16x8*)&Vsm[(n * 16 + cl) * LSTR + ko];
        oacc[n] = __builtin_amdgcn_mfma_f32_16x16x32_bf16(pa, vb, oacc[n], 0, 0, 0);
      }
    }
    __syncthreads();
  }
  // write O / l
  #pragma unroll
  for (int n = 0; n < 4; ++n)
    #pragma unroll
    for (int j = 0; j < 4; ++j) {
      int qg = qb * 64 + wave * 16 + gp * 4 + j;
      int d = n * 16 + cl;
      out[(size_t)(b * SEQLEN + qg) * HIDDEN + h * HDIM + d] = oacc[n][j] / lrow[j];
    }
}

extern "C" void kernel_launch(void* const* d_in, const int* in_sizes, int n_in,
                              void* d_out, int out_size, void* d_ws, size_t ws_size,
                              hipStream_t stream) {
  const int*   ids    = (const int*)d_in[0];
  const float* W_word = (const float*)d_in[1];
  const float* W_pos  = (const float*)d_in[2];
  const float* Wq     = (const float*)d_in[3];
  const float* Wk     = (const float*)d_in[4];
  const float* Wv     = (const float*)d_in[5];
  const float* Wo     = (const float*)d_in[6];
  const float* W1     = (const float*)d_in[7];
  const float* W2     = (const float*)d_in[8];
  const float* W_eh   = (const float*)d_in[9];
  const float* W_he   = (const float*)d_in[10];
  const float* W_lm   = (const float*)d_in[11];
  float* out = (float*)d_out;

  // scratch layout inside d_out (131M floats; logits written last):
  const size_t MEG = 1024 * 1024;
  float* x    = out;              // [4096,4096] = 16.78M floats, 0..16.78M
  float* qkv  = out + 17 * MEG;   // [4096,3072] = 12.58M
  float* h0   = out + 30 * MEG;   // [4096,512]  = 2M
  float* h1   = out + 32 * MEG;   // [4096,1024] = 4M
  float* attn = out + 36 * MEG;   // [4096,1024] = 4M
  float* he   = (float*)d_ws;     // [4096,512]  = 2M floats (8 MB) — must NOT be in d_out

  embed_kernel<<<dim3(ROWS), dim3(128), 0, stream>>>(ids, W_word, W_pos, h0);
  // h1 = h0 @ W_eh.T              M=4096 K=512  N=1024
  gemm_bt<0><<<dim3(32, 8), 256, 0, stream>>>(h0, W_eh, h1, nullptr, 512, HIDDEN);
  // qkv (three slices, ldc=3072)  M=4096 K=1024 N=1024 each
  gemm_bt<0><<<dim3(32, 8), 256, 0, stream>>>(h1, Wq, qkv + 0,      nullptr, 1024, 3 * HIDDEN);
  gemm_bt<0><<<dim3(32, 8), 256, 0, stream>>>(h1, Wk, qkv + 1024,   nullptr, 1024, 3 * HIDDEN);
  gemm_bt<0><<<dim3(32, 8), 256, 0, stream>>>(h1, Wv, qkv + 2048,   nullptr, 1024, 3 * HIDDEN);
  // attention
  attn_kernel<<<dim3(16, 16, 4), 256, 0, stream>>>(qkv, attn);
  // h1 = h1 + attn @ Wo.T (in place)
  gemm_bt<1><<<dim3(32, 8), 256, 0, stream>>>(attn, Wo, h1, h1, 1024, HIDDEN);
  // x = relu(h1 @ W1.T)           M=4096 K=1024 N=4096
  gemm_bt<2><<<dim3(32, 32), 256, 0, stream>>>(h1, W1, x, nullptr, 1024, 4 * HIDDEN);
  // h1 = h1 + x @ W2.T (in place) M=4096 K=4096 N=1024
  gemm_bt<1><<<dim3(32, 8), 256, 0, stream>>>(x, W2, h1, h1, 4096, HIDDEN);
  // he = h1 @ W_he.T              M=4096 K=1024 N=512
  gemm_bt<0><<<dim3(32, 4), 256, 0, stream>>>(h1, W_he, he, nullptr, 1024, EMBED);
  // logits = he @ W_lm.T          M=4096 K=512  N=32000
  gemm_bt<0><<<dim3(32, 250), 256, 0, stream>>>(he, W_lm, out, nullptr, 512, VOCAB);
}

// Round 2
// 763.542 us; speedup vs baseline: 1.7853x; 1.7853x over previous
//
#include <hip/hip_runtime.h>
#include <hip/hip_bf16.h>

#define HIDDEN 1024
#define NHEAD 16
#define HDIM 64
#define VOCAB 32000
#define SEQLEN 1024
#define EMBED 512
#define BATCH 4
#define ROWS (BATCH*SEQLEN)   // 4096

typedef __bf16 bf16x8 __attribute__((ext_vector_type(8)));
typedef float f32x4 __attribute__((ext_vector_type(4)));
typedef unsigned short u16;

__device__ __forceinline__ u16 f2bf(float f) {
  unsigned u = __builtin_bit_cast(unsigned, f);
  u = u + 0x7FFFu + ((u >> 16) & 1u);
  return (u16)(u >> 16);
}

// async global->LDS, 16B per lane; lds dest is wave-uniform base + lane*16
#define GLDS(g_, l_) __builtin_amdgcn_global_load_lds( \
    (const __attribute__((address_space(1))) void*)(g_), \
    (__attribute__((address_space(3))) void*)(l_), 16, 0, 0)

// ---------------- f32 -> bf16 conversion (weights), 4 elems/thread
__global__ void cvt_kernel(const float* __restrict__ in, u16* __restrict__ out) {
  size_t i = ((size_t)blockIdx.x * 256 + threadIdx.x) * 4;
  float4 v = *(const float4*)(in + i);
  unsigned a = f2bf(v.x) | ((unsigned)f2bf(v.y) << 16);
  unsigned b = f2bf(v.z) | ((unsigned)f2bf(v.w) << 16);
  *(uint2*)(out + i) = make_uint2(a, b);
}

// ---------------- embedding -> bf16: h0b[row][e] = bf16(W_word[ids[row]][e] + W_pos[row%S][e])
__global__ void embed_kernel(const int* __restrict__ ids,
                             const float* __restrict__ W_word,
                             const float* __restrict__ W_pos,
                             u16* __restrict__ out) {
  int row = blockIdx.x;
  int s = row & (SEQLEN - 1);
  int id = ids[row];
  int e = threadIdx.x * 4;
  float4 a = *(const float4*)(W_word + (size_t)id * EMBED + e);
  float4 b = *(const float4*)(W_pos + (size_t)s * EMBED + e);
  unsigned lo = f2bf(a.x + b.x) | ((unsigned)f2bf(a.y + b.y) << 16);
  unsigned hi = f2bf(a.z + b.z) | ((unsigned)f2bf(a.w + b.w) << 16);
  *(uint2*)(out + (size_t)row * EMBED + e) = make_uint2(lo, hi);
}

// ---------------- GEMM (m97 structure): C[m,n] = sum_k A[m,k]*B[n,k] (+epilogue)
// A: [M,K] bf16.  B: [N,K] bf16 (or f32 if BF32: stage-convert through regs).
// EPI: 0 none, 1 += R (f32), 2 relu.  WF32: write f32 C.  WB16: write bf16 Cb.
template<int EPI, bool WF32, bool WB16, bool BF32, bool SWZ>
__global__ __launch_bounds__(256) void gemm_bf(
    const u16* __restrict__ A, const u16* __restrict__ Bb,
    const float* __restrict__ Bf,
    float* __restrict__ C, u16* __restrict__ Cb,
    const float* __restrict__ R, int K, int ldc)
{
  __shared__ u16 As[128 * 64];
  __shared__ u16 Bs[128 * 64];
  int tid = threadIdx.x;
  int lane = tid & 63, wave = tid >> 6;
  int wr = wave >> 1, wc = wave & 1;
  int cl = lane & 15, gp = lane >> 4;

  int bx = blockIdx.x, by = blockIdx.y;
  if (SWZ) {
    int nwg = gridDim.x * gridDim.y;        // divisible by 8 for all our grids
    int flat = by * gridDim.x + bx;
    int cpx = nwg >> 3;
    int swz = (flat & 7) * cpx + (flat >> 3);
    bx = swz % gridDim.x;
    by = swz / gridDim.x;
  }
  int m0 = bx * 128, n0 = by * 128;

  int srow = lane >> 3;            // 0..7 (row within 8-row chunk)
  int scol = (lane & 7) * 8;       // elem col within BK=64

  f32x4 acc[4][4] = {};
  int nk = K >> 6;
  for (int kt = 0; kt < nk; ++kt) {
    int kb = kt << 6;
    #pragma unroll
    for (int it = 0; it < 4; ++it) {
      int c = it * 4 + wave;       // chunk 0..15, 1KB each, wave-uniform
      int row = c * 8 + srow;
      GLDS(A + (size_t)(m0 + row) * K + kb + scol, &As[c * 512]);
    }
    if (!BF32) {
      #pragma unroll
      for (int it = 0; it < 4; ++it) {
        int c = it * 4 + wave;
        int row = c * 8 + srow;
        GLDS(Bb + (size_t)(n0 + row) * K + kb + scol, &Bs[c * 512]);
      }
    } else {
      #pragma unroll
      for (int it = 0; it < 8; ++it) {
        int idx = it * 256 + tid;
        int row = idx >> 4;
        int c4 = (idx & 15) * 4;
        float4 bv = *(const float4*)(Bf + (size_t)(n0 + row) * K + kb + c4);
        unsigned b01 = f2bf(bv.x) | ((unsigned)f2bf(bv.y) << 16);
        unsigned b23 = f2bf(bv.z) | ((unsigned)f2bf(bv.w) << 16);
        *(uint2*)&Bs[row * 64 + c4] = make_uint2(b01, b23);
      }
    }
    __syncthreads();
    #pragma unroll
    for (int ks = 0; ks < 2; ++ks) {
      int ko = ks * 32 + gp * 8;
      bf16x8 af[4], bfv[4];
      #pragma unroll
      for (int m = 0; m < 4; ++m)
        af[m] = *(const bf16x8*)&As[(wr * 64 + m * 16 + cl) * 64 + ko];
      #pragma unroll
      for (int n = 0; n < 4; ++n)
        bfv[n] = *(const bf16x8*)&Bs[(wc * 64 + n * 16 + cl) * 64 + ko];
      #pragma unroll
      for (int m = 0; m < 4; ++m)
        #pragma unroll
        for (int n = 0; n < 4; ++n)
          acc[m][n] = __builtin_amdgcn_mfma_f32_16x16x32_bf16(af[m], bfv[n], acc[m][n], 0, 0, 0);
    }
    __syncthreads();
  }
  // epilogue: C/D layout col = lane&15, row = (lane>>4)*4 + j
  int r0 = gp * 4;
  #pragma unroll
  for (int m = 0; m < 4; ++m) {
    #pragma unroll
    for (int n = 0; n < 4; ++n) {
      int col = n0 + wc * 64 + n * 16 + cl;
      #pragma unroll
      for (int j = 0; j < 4; ++j) {
        int row = m0 + wr * 64 + m * 16 + r0 + j;
        float v = acc[m][n][j];
        if (EPI == 1) v += R[(size_t)row * ldc + col];
        if (EPI == 2) v = fmaxf(v, 0.f);
        if (WF32) C[(size_t)row * ldc + col] = v;
        if (WB16) Cb[(size_t)row * ldc + col] = f2bf(v);
      }
    }
  }
}

// ---------------- fused causal attention, bf16 qkv in, bf16 out
#define LSTR 72
__global__ __launch_bounds__(256) void attn_kernel(const u16* __restrict__ qkv,
                                                   u16* __restrict__ outb) {
  __shared__ u16 Ksm[64 * LSTR];
  __shared__ u16 Vsm[64 * LSTR];   // transposed: [d][k]
  __shared__ u16 Psm[64 * LSTR];
  int qb = blockIdx.x, h = blockIdx.y, b = blockIdx.z;
  int tid = threadIdx.x;
  int lane = tid & 63, wave = tid >> 6;
  int cl = lane & 15, gp = lane >> 4;

  const u16* base = qkv + (size_t)b * SEQLEN * (3 * HIDDEN);

  int qrow_a = qb * 64 + wave * 16 + cl;
  bf16x8 qf[2];
  {
    const u16* qp = base + (size_t)qrow_a * (3 * HIDDEN) + h * HDIM;
    qf[0] = *(const bf16x8*)(qp + gp * 8);
    qf[1] = *(const bf16x8*)(qp + 32 + gp * 8);
  }

  float mrow[4], lrow[4];
  f32x4 oacc[4] = {};
  #pragma unroll
  for (int j = 0; j < 4; ++j) { mrow[j] = -INFINITY; lrow[j] = 0.f; }

  for (int t = 0; t <= qb; ++t) {
    #pragma unroll
    for (int it = 0; it < 4; ++it) {
      int idx = it * 256 + tid;
      int row = idx >> 4;
      int c4 = (idx & 15) * 4;
      const u16* kp = base + (size_t)(t * 64 + row) * (3 * HIDDEN) + HIDDEN + h * HDIM + c4;
      const u16* vp = base + (size_t)(t * 64 + row) * (3 * HIDDEN) + 2 * HIDDEN + h * HDIM + c4;
      *(uint2*)&Ksm[row * LSTR + c4] = *(const uint2*)kp;
      ushort4 vv = *(const ushort4*)vp;
      Vsm[(c4 + 0) * LSTR + row] = vv.x;
      Vsm[(c4 + 1) * LSTR + row] = vv.y;
      Vsm[(c4 + 2) * LSTR + row] = vv.z;
      Vsm[(c4 + 3) * LSTR + row] = vv.w;
    }
    __syncthreads();

    f32x4 sfr[4];
    #pragma unroll
    for (int n = 0; n < 4; ++n) {
      f32x4 z = {};
      #pragma unroll
      for (int ks = 0; ks < 2; ++ks) {
        int ko = ks * 32 + gp * 8;
        bf16x8 kf = *(const bf16x8*)&Ksm[(n * 16 + cl) * LSTR + ko];
        z = __builtin_amdgcn_mfma_f32_16x16x32_bf16(qf[ks], kf, z, 0, 0, 0);
      }
      sfr[n] = z;
    }
    #pragma unroll
    for (int n = 0; n < 4; ++n)
      #pragma unroll
      for (int j = 0; j < 4; ++j) {
        int qg = qb * 64 + wave * 16 + gp * 4 + j;
        int kg = t * 64 + n * 16 + cl;
        float sv = sfr[n][j] * 0.03125f;
        sfr[n][j] = (kg <= qg) ? sv : -1e30f;
      }
    float so[4];
    #pragma unroll
    for (int j = 0; j < 4; ++j) {
      float tm = fmaxf(fmaxf(sfr[0][j], sfr[1][j]), fmaxf(sfr[2][j], sfr[3][j]));
      tm = fmaxf(tm, __shfl_xor(tm, 1));
      tm = fmaxf(tm, __shfl_xor(tm, 2));
      tm = fmaxf(tm, __shfl_xor(tm, 4));
      tm = fmaxf(tm, __shfl_xor(tm, 8));
      float mn = fmaxf(mrow[j], tm);
      so[j] = expf(mrow[j] - mn);
      mrow[j] = mn;
      float ts = 0.f;
      #pragma unroll
      for (int n = 0; n < 4; ++n) {
        float p = expf(sfr[n][j] - mn);
        sfr[n][j] = p;
        ts += p;
      }
      ts += __shfl_xor(ts, 1); ts += __shfl_xor(ts, 2);
      ts += __shfl_xor(ts, 4); ts += __shfl_xor(ts, 8);
      lrow[j] = lrow[j] * so[j] + ts;
    }
    #pragma unroll
    for (int n = 0; n < 4; ++n)
      #pragma unroll
      for (int j = 0; j < 4; ++j)
        oacc[n][j] *= so[j];
    #pragma unroll
    for (int n = 0; n < 4; ++n)
      #pragma unroll
      for (int j = 0; j < 4; ++j)
        Psm[(wave * 16 + gp * 4 + j) * LSTR + n * 16 + cl] = f2bf(sfr[n][j]);
    __syncthreads();  // Psm written by scatter; ensure visible (also protects Ksm reuse)
    #pragma unroll
    for (int n = 0; n < 4; ++n) {
      #pragma unroll
      for (int ks = 0; ks < 2; ++ks) {
        int ko = ks * 32 + gp * 8;
        bf16x8 pa = *(const bf16x8*)&Psm[(wave * 16 + cl) * LSTR + ko];
        bf16x8 vb = *(const bf16x8*)&Vsm[(n * 16 + cl) * LSTR + ko];
        oacc[n] = __builtin_amdgcn_mfma_f32_16x16x32_bf16(pa, vb, oacc[n], 0, 0, 0);
      }
    }
    __syncthreads();
  }
  #pragma unroll
  for (int n = 0; n < 4; ++n)
    #pragma unroll
    for (int j = 0; j < 4; ++j) {
      int qg = qb * 64 + wave * 16 + gp * 4 + j;
      int d = n * 16 + cl;
      outb[(size_t)(b * SEQLEN + qg) * HIDDEN + h * HDIM + d] = f2bf(oacc[n][j] / lrow[j]);
    }
}

extern "C" void kernel_launch(void* const* d_in, const int* in_sizes, int n_in,
                              void* d_out, int out_size, void* d_ws, size_t ws_size,
                              hipStream_t stream) {
  const int*   ids    = (const int*)d_in[0];
  const float* W_word = (const float*)d_in[1];
  const float* W_pos  = (const float*)d_in[2];
  const float* Wq     = (const float*)d_in[3];
  const float* Wk     = (const float*)d_in[4];
  const float* Wv     = (const float*)d_in[5];
  const float* Wo     = (const float*)d_in[6];
  const float* W1     = (const float*)d_in[7];
  const float* W2     = (const float*)d_in[8];
  const float* W_eh   = (const float*)d_in[9];
  const float* W_he   = (const float*)d_in[10];
  const float* W_lm   = (const float*)d_in[11];
  float* out = (float*)d_out;
  char*  ob  = (char*)d_out;
  char*  wb  = (char*)d_ws;

  // ---- scratch layout in d_out (bytes; all overwritten by the LM head last)
  const size_t MB = 1024 * 1024;
  float* h1    = (float*)(ob + 0 * MB);    // [4096,1024] f32, 16MB
  float* h2    = (float*)(ob + 16 * MB);   // [4096,1024] f32, 16MB
  u16*   h0b   = (u16*)(ob + 32 * MB);     // [4096,512]  4MB
  u16*   h1b   = (u16*)(ob + 36 * MB);     // [4096,1024] 8MB
  u16*   qkvb  = (u16*)(ob + 44 * MB);     // [4096,3072] 24MB
  u16*   attnb = (u16*)(ob + 68 * MB);     // [4096,1024] 8MB
  u16*   h2b   = (u16*)(ob + 76 * MB);     // [4096,1024] 8MB
  u16*   xb    = (u16*)(ob + 84 * MB);     // [4096,4096] 32MB
  u16*   h3b   = (u16*)(ob + 116 * MB);    // [4096,1024] 8MB
  u16*   Wq_b  = (u16*)(ob + 124 * MB);
  u16*   Wk_b  = (u16*)(ob + 126 * MB);
  u16*   Wv_b  = (u16*)(ob + 128 * MB);
  u16*   Wo_b  = (u16*)(ob + 130 * MB);
  u16*   W1_b  = (u16*)(ob + 132 * MB);    // 8MB
  u16*   W2_b  = (u16*)(ob + 140 * MB);    // 8MB
  u16*   Weh_b = (u16*)(ob + 148 * MB);    // 1MB
  u16*   Whe_b = (u16*)(ob + 149 * MB);    // 1MB
  // ---- d_ws: read by the LM-head GEMM while it writes all of d_out
  u16*   he_b  = (u16*)(wb + 0);           // [4096,512]  4MB
  u16*   Wlm_b = (u16*)(wb + 4 * MB);      // [32000,512] 32MB (if ws fits)
  bool big_ws = ws_size >= 36 * MB;

  // weight conversions (grid = n/1024, all sizes divisible by 1024)
  cvt_kernel<<<dim3(1024), 256, 0, stream>>>(Wq, Wq_b);
  cvt_kernel<<<dim3(1024), 256, 0, stream>>>(Wk, Wk_b);
  cvt_kernel<<<dim3(1024), 256, 0, stream>>>(Wv, Wv_b);
  cvt_kernel<<<dim3(1024), 256, 0, stream>>>(Wo, Wo_b);
  cvt_kernel<<<dim3(4096), 256, 0, stream>>>(W1, W1_b);
  cvt_kernel<<<dim3(4096), 256, 0, stream>>>(W2, W2_b);
  cvt_kernel<<<dim3(512),  256, 0, stream>>>(W_eh, Weh_b);
  cvt_kernel<<<dim3(512),  256, 0, stream>>>(W_he, Whe_b);
  if (big_ws)
    cvt_kernel<<<dim3(16000), 256, 0, stream>>>(W_lm, Wlm_b);

  embed_kernel<<<dim3(ROWS), 128, 0, stream>>>(ids, W_word, W_pos, h0b);

  // h1 = h0 @ W_eh.T   (f32 + bf16)
  gemm_bf<0, true, true, false, false><<<dim3(32, 8), 256, 0, stream>>>(
      h0b, Weh_b, nullptr, h1, h1b, nullptr, 512, HIDDEN);
  // qkv projections (bf16 only, ldc=3072)
  gemm_bf<0, false, true, false, false><<<dim3(32, 8), 256, 0, stream>>>(
      h1b, Wq_b, nullptr, nullptr, qkvb + 0, nullptr, 1024, 3 * HIDDEN);
  gemm_bf<0, false, true, false, false><<<dim3(32, 8), 256, 0, stream>>>(
      h1b, Wk_b, nullptr, nullptr, qkvb + 1024, nullptr, 1024, 3 * HIDDEN);
  gemm_bf<0, false, true, false, false><<<dim3(32, 8), 256, 0, stream>>>(
      h1b, Wv_b, nullptr, nullptr, qkvb + 2048, nullptr, 1024, 3 * HIDDEN);
  // attention
  attn_kernel<<<dim3(16, 16, 4), 256, 0, stream>>>(qkvb, attnb);
  // h2 = h1 + attn @ Wo.T  (f32 + bf16)
  gemm_bf<1, true, true, false, false><<<dim3(32, 8), 256, 0, stream>>>(
      attnb, Wo_b, nullptr, h2, h2b, h1, 1024, HIDDEN);
  // x = relu(h2 @ W1.T)  (bf16 only)
  gemm_bf<2, false, true, false, false><<<dim3(32, 32), 256, 0, stream>>>(
      h2b, W1_b, nullptr, nullptr, xb, nullptr, 1024, 4 * HIDDEN);
  // h3 = h2 + x @ W2.T  (bf16 only; residual f32 read)
  gemm_bf<1, false, true, false, false><<<dim3(32, 8), 256, 0, stream>>>(
      xb, W2_b, nullptr, nullptr, h3b, h2, 4096, HIDDEN);
  // he = h3 @ W_he.T  (bf16, into d_ws)
  gemm_bf<0, false, true, false, false><<<dim3(32, 4), 256, 0, stream>>>(
      h3b, Whe_b, nullptr, nullptr, he_b, nullptr, 1024, EMBED);
  // logits = he @ W_lm.T  (f32 out = entire d_out; XCD swizzle)
  if (big_ws)
    gemm_bf<0, true, false, false, true><<<dim3(32, 250), 256, 0, stream>>>(
        he_b, Wlm_b, nullptr, out, nullptr, nullptr, 512, VOCAB);
  else
    gemm_bf<0, true, false, true, true><<<dim3(32, 250), 256, 0, stream>>>(
        he_b, nullptr, W_lm, out, nullptr, nullptr, 512, VOCAB);
}

// Round 4
// 585.429 us; speedup vs baseline: 2.3285x; 1.3042x over previous
//
#include <hip/hip_runtime.h>
#include <hip/hip_bf16.h>

#define HIDDEN 1024
#define NHEAD 16
#define HDIM 64
#define VOCAB 32000
#define SEQLEN 1024
#define EMBED 512
#define BATCH 4
#define ROWS (BATCH*SEQLEN)   // 4096

typedef __bf16 bf16x8 __attribute__((ext_vector_type(8)));
typedef float f32x4 __attribute__((ext_vector_type(4)));
typedef unsigned short u16;

#define MFMA(a_, b_, c_) __builtin_amdgcn_mfma_f32_16x16x32_bf16(a_, b_, c_, 0, 0, 0)

__device__ __forceinline__ u16 f2bf(float f) {
  unsigned u = __builtin_bit_cast(unsigned, f);
  u = u + 0x7FFFu + ((u >> 16) & 1u);
  return (u16)(u >> 16);
}

// async global->LDS, 16B/lane; LDS dest = wave-uniform base + lane*16
#define GLDS(g_, l_) __builtin_amdgcn_global_load_lds( \
    (const __attribute__((address_space(1))) void*)(g_), \
    (__attribute__((address_space(3))) void*)(l_), 16, 0, 0)

// ---------------- f32 -> bf16 conversion
__global__ void cvt_kernel(const float* __restrict__ in, u16* __restrict__ out) {
  size_t i = ((size_t)blockIdx.x * 256 + threadIdx.x) * 4;
  float4 v = *(const float4*)(in + i);
  unsigned a = f2bf(v.x) | ((unsigned)f2bf(v.y) << 16);
  unsigned b = f2bf(v.z) | ((unsigned)f2bf(v.w) << 16);
  *(uint2*)(out + i) = make_uint2(a, b);
}

// ---------------- embedding -> bf16
__global__ void embed_kernel(const int* __restrict__ ids,
                             const float* __restrict__ W_word,
                             const float* __restrict__ W_pos,
                             u16* __restrict__ out) {
  int row = blockIdx.x;
  int s = row & (SEQLEN - 1);
  int id = ids[row];
  int e = threadIdx.x * 4;
  float4 a = *(const float4*)(W_word + (size_t)id * EMBED + e);
  float4 b = *(const float4*)(W_pos + (size_t)s * EMBED + e);
  unsigned lo = f2bf(a.x + b.x) | ((unsigned)f2bf(a.y + b.y) << 16);
  unsigned hi = f2bf(a.z + b.z) | ((unsigned)f2bf(a.w + b.w) << 16);
  *(uint2*)(out + (size_t)row * EMBED + e) = make_uint2(lo, hi);
}

// ======================================================================
// 128x128 GEMM, 4 waves, dbuf LDS, rotation-swizzled, 1 barrier/K-tile.
// C[m,n] = sum_k A[m,k]*B[n,k].  EPI: 0 none, 1 +=R(f32), 2 relu.
template<int EPI, bool WF32, bool WB16, bool BF32, bool SWZ>
__global__ __launch_bounds__(256, 2) void gemm128(
    const u16* __restrict__ A, const u16* __restrict__ Bb,
    const float* __restrict__ Bf,
    float* __restrict__ C, u16* __restrict__ Cb,
    const float* __restrict__ R, int K, int ldc)
{
  __shared__ u16 As[2][128 * 64];
  __shared__ u16 Bs[2][128 * 64];
  int tid = threadIdx.x;
  int lane = tid & 63, wave = tid >> 6;
  int wr = wave >> 1, wc = wave & 1;
  int cl = lane & 15, gp = (lane >> 4) & 3;

  int bx = blockIdx.x, by = blockIdx.y;
  if (SWZ) {
    int nwg = gridDim.x * gridDim.y;
    int flat = by * gridDim.x + bx;
    int cpx = nwg >> 3;
    int swz = (flat & 7) * cpx + (flat >> 3);
    bx = swz % gridDim.x; by = swz / gridDim.x;
  }
  int m0 = bx * 128, n0 = by * 128;

  int srow8 = lane >> 3;                         // row within 8-row chunk
  int scol = (((lane & 7) - srow8) & 7) * 8;     // rotated global source col
  int pos0 = ((gp + cl) & 7) * 8;                // rotated read offset, ks=0
  int pos1 = ((gp + cl + 4) & 7) * 8;            // ks=1

  f32x4 acc[4][4] = {};
  int nk = K >> 6;

  // prologue: stage tile 0 -> buf 0
  #pragma unroll
  for (int i = 0; i < 4; ++i) {
    int c = i * 4 + wave;
    int row = c * 8 + srow8;
    GLDS(A + (size_t)(m0 + row) * K + scol, &As[0][c * 512]);
    if (!BF32) GLDS(Bb + (size_t)(n0 + row) * K + scol, &Bs[0][c * 512]);
  }
  if (BF32) {
    #pragma unroll
    for (int it = 0; it < 4; ++it) {
      int idx = it * 256 + tid;
      int row = idx >> 3, p = idx & 7;
      int gc = (p - row) & 7;
      const float* src = Bf + (size_t)(n0 + row) * K + gc * 8;
      float4 v0 = *(const float4*)src, v1 = *(const float4*)(src + 4);
      union { bf16x8 v; u16 s[8]; } u;
      u.s[0]=f2bf(v0.x); u.s[1]=f2bf(v0.y); u.s[2]=f2bf(v0.z); u.s[3]=f2bf(v0.w);
      u.s[4]=f2bf(v1.x); u.s[5]=f2bf(v1.y); u.s[6]=f2bf(v1.z); u.s[7]=f2bf(v1.w);
      *(bf16x8*)&Bs[0][row * 64 + p * 8] = u.v;
    }
  }
  __syncthreads();

  for (int kt = 0; kt < nk; ++kt) {
    int buf = kt & 1;
    int kb = (kt + 1) << 6;
    bool more = kt + 1 < nk;
    bf16x8 af[2][2], bfr[4][2];

    // ---- phase 0: stage next-A; read B(all)+A(mh=0); MFMA Q00
    if (more) {
      #pragma unroll
      for (int i = 0; i < 4; ++i) {
        int c = i * 4 + wave;
        GLDS(A + (size_t)(m0 + c * 8 + srow8) * K + kb + scol, &As[buf ^ 1][c * 512]);
      }
    }
    #pragma unroll
    for (int n = 0; n < 4; ++n) {
      int r = (wc * 64 + n * 16 + cl) * 64;
      bfr[n][0] = *(const bf16x8*)&Bs[buf][r + pos0];
      bfr[n][1] = *(const bf16x8*)&Bs[buf][r + pos1];
    }
    #pragma unroll
    for (int m = 0; m < 2; ++m) {
      int r = (wr * 64 + m * 16 + cl) * 64;
      af[m][0] = *(const bf16x8*)&As[buf][r + pos0];
      af[m][1] = *(const bf16x8*)&As[buf][r + pos1];
    }
    __builtin_amdgcn_s_setprio(1);
    #pragma unroll
    for (int m = 0; m < 2; ++m)
      #pragma unroll
      for (int n = 0; n < 2; ++n)
        #pragma unroll
        for (int ks = 0; ks < 2; ++ks)
          acc[m][n] = MFMA(af[m][ks], bfr[n][ks], acc[m][n]);
    __builtin_amdgcn_s_setprio(0);

    // ---- phase 1: stage next-B; MFMA Q01
    if (more) {
      if (!BF32) {
        #pragma unroll
        for (int i = 0; i < 4; ++i) {
          int c = i * 4 + wave;
          GLDS(Bb + (size_t)(n0 + c * 8 + srow8) * K + kb + scol, &Bs[buf ^ 1][c * 512]);
        }
      } else {
        #pragma unroll
        for (int it = 0; it < 4; ++it) {
          int idx = it * 256 + tid;
          int row = idx >> 3, p = idx & 7;
          int gc = (p - row) & 7;
          const float* src = Bf + (size_t)(n0 + row) * K + kb + gc * 8;
          float4 v0 = *(const float4*)src, v1 = *(const float4*)(src + 4);
          union { bf16x8 v; u16 s[8]; } u;
          u.s[0]=f2bf(v0.x); u.s[1]=f2bf(v0.y); u.s[2]=f2bf(v0.z); u.s[3]=f2bf(v0.w);
          u.s[4]=f2bf(v1.x); u.s[5]=f2bf(v1.y); u.s[6]=f2bf(v1.z); u.s[7]=f2bf(v1.w);
          *(bf16x8*)&Bs[buf ^ 1][row * 64 + p * 8] = u.v;
        }
      }
    }
    __builtin_amdgcn_s_setprio(1);
    #pragma unroll
    for (int m = 0; m < 2; ++m)
      #pragma unroll
      for (int n = 2; n < 4; ++n)
        #pragma unroll
        for (int ks = 0; ks < 2; ++ks)
          acc[m][n] = MFMA(af[m][ks], bfr[n][ks], acc[m][n]);
    __builtin_amdgcn_s_setprio(0);

    // ---- phase 2: read A(mh=1); MFMA Q10
    #pragma unroll
    for (int m = 0; m < 2; ++m) {
      int r = (wr * 64 + (m + 2) * 16 + cl) * 64;
      af[m][0] = *(const bf16x8*)&As[buf][r + pos0];
      af[m][1] = *(const bf16x8*)&As[buf][r + pos1];
    }
    __builtin_amdgcn_s_setprio(1);
    #pragma unroll
    for (int m = 0; m < 2; ++m)
      #pragma unroll
      for (int n = 0; n < 2; ++n)
        #pragma unroll
        for (int ks = 0; ks < 2; ++ks)
          acc[m + 2][n] = MFMA(af[m][ks], bfr[n][ks], acc[m + 2][n]);
    __builtin_amdgcn_s_setprio(0);

    // ---- phase 3: MFMA Q11
    __builtin_amdgcn_s_setprio(1);
    #pragma unroll
    for (int m = 0; m < 2; ++m)
      #pragma unroll
      for (int n = 2; n < 4; ++n)
        #pragma unroll
        for (int ks = 0; ks < 2; ++ks)
          acc[m + 2][n] = MFMA(af[m][ks], bfr[n][ks], acc[m + 2][n]);
    __builtin_amdgcn_s_setprio(0);

    __syncthreads();
  }

  int r0 = gp * 4;
  #pragma unroll
  for (int m = 0; m < 4; ++m) {
    #pragma unroll
    for (int n = 0; n < 4; ++n) {
      int col = n0 + wc * 64 + n * 16 + cl;
      #pragma unroll
      for (int j = 0; j < 4; ++j) {
        int row = m0 + wr * 64 + m * 16 + r0 + j;
        float v = acc[m][n][j];
        if (EPI == 1) v += R[(size_t)row * ldc + col];
        if (EPI == 2) v = fmaxf(v, 0.f);
        if (WF32) C[(size_t)row * ldc + col] = v;
        if (WB16) Cb[(size_t)row * ldc + col] = f2bf(v);
      }
    }
  }
}

// ======================================================================
// 256x256 GEMM, 8 waves (2Mx4N), 128KB dbuf LDS, rotation-swizzled.
template<int EPI, bool WF32, bool WB16, bool SWZ>
__global__ __launch_bounds__(512) void gemm256(
    const u16* __restrict__ A, const u16* __restrict__ B,
    float* __restrict__ C, u16* __restrict__ Cb,
    const float* __restrict__ R, int K, int ldc)
{
  __shared__ u16 As[2][256 * 64];
  __shared__ u16 Bs[2][256 * 64];
  int tid = threadIdx.x;
  int lane = tid & 63, wave = tid >> 6;          // 8 waves
  int wr = wave >> 2, wc = wave & 3;             // 2 x 4
  int cl = lane & 15, gp = (lane >> 4) & 3;

  int bx = blockIdx.x, by = blockIdx.y;
  if (SWZ) {
    int nwg = gridDim.x * gridDim.y;
    int flat = by * gridDim.x + bx;
    int cpx = nwg >> 3;
    int swz = (flat & 7) * cpx + (flat >> 3);
    bx = swz % gridDim.x; by = swz / gridDim.x;
  }
  int m0 = bx * 256, n0 = by * 256;

  int srow8 = lane >> 3;
  int scol = (((lane & 7) - srow8) & 7) * 8;
  int pos0 = ((gp + cl) & 7) * 8;
  int pos1 = ((gp + cl + 4) & 7) * 8;

  f32x4 acc[8][4] = {};
  int nk = K >> 6;

  // prologue: stage tile 0
  #pragma unroll
  for (int i = 0; i < 4; ++i) {
    int c = i * 8 + wave;
    int row = c * 8 + srow8;
    GLDS(A + (size_t)(m0 + row) * K + scol, &As[0][c * 512]);
    GLDS(B + (size_t)(n0 + row) * K + scol, &Bs[0][c * 512]);
  }
  __syncthreads();

  for (int kt = 0; kt < nk; ++kt) {
    int buf = kt & 1;
    int kb = (kt + 1) << 6;
    bool more = kt + 1 < nk;
    bf16x8 af[4][2], bfr[4][2];

    // ---- phase 0: stage next-A; read B(all) + A(mh=0); MFMA Q00 (16)
    if (more) {
      #pragma unroll
      for (int i = 0; i < 4; ++i) {
        int c = i * 8 + wave;
        GLDS(A + (size_t)(m0 + c * 8 + srow8) * K + kb + scol, &As[buf ^ 1][c * 512]);
      }
    }
    #pragma unroll
    for (int n = 0; n < 4; ++n) {
      int r = (wc * 64 + n * 16 + cl) * 64;
      bfr[n][0] = *(const bf16x8*)&Bs[buf][r + pos0];
      bfr[n][1] = *(const bf16x8*)&Bs[buf][r + pos1];
    }
    #pragma unroll
    for (int m = 0; m < 4; ++m) {
      int r = (wr * 128 + m * 16 + cl) * 64;
      af[m][0] = *(const bf16x8*)&As[buf][r + pos0];
      af[m][1] = *(const bf16x8*)&As[buf][r + pos1];
    }
    __builtin_amdgcn_s_setprio(1);
    #pragma unroll
    for (int m = 0; m < 4; ++m)
      #pragma unroll
      for (int n = 0; n < 2; ++n)
        #pragma unroll
        for (int ks = 0; ks < 2; ++ks)
          acc[m][n] = MFMA(af[m][ks], bfr[n][ks], acc[m][n]);
    __builtin_amdgcn_s_setprio(0);

    // ---- phase 1: stage next-B; MFMA Q01
    if (more) {
      #pragma unroll
      for (int i = 0; i < 4; ++i) {
        int c = i * 8 + wave;
        GLDS(B + (size_t)(n0 + c * 8 + srow8) * K + kb + scol, &Bs[buf ^ 1][c * 512]);
      }
    }
    __builtin_amdgcn_s_setprio(1);
    #pragma unroll
    for (int m = 0; m < 4; ++m)
      #pragma unroll
      for (int n = 2; n < 4; ++n)
        #pragma unroll
        for (int ks = 0; ks < 2; ++ks)
          acc[m][n] = MFMA(af[m][ks], bfr[n][ks], acc[m][n]);
    __builtin_amdgcn_s_setprio(0);

    // ---- phase 2: read A(mh=1); MFMA Q10
    #pragma unroll
    for (int m = 0; m < 4; ++m) {
      int r = (wr * 128 + (m + 4) * 16 + cl) * 64;
      af[m][0] = *(const bf16x8*)&As[buf][r + pos0];
      af[m][1] = *(const bf16x8*)&As[buf][r + pos1];
    }
    __builtin_amdgcn_s_setprio(1);
    #pragma unroll
    for (int m = 0; m < 4; ++m)
      #pragma unroll
      for (int n = 0; n < 2; ++n)
        #pragma unroll
        for (int ks = 0; ks < 2; ++ks)
          acc[m + 4][n] = MFMA(af[m][ks], bfr[n][ks], acc[m + 4][n]);
    __builtin_amdgcn_s_setprio(0);

    // ---- phase 3: MFMA Q11
    __builtin_amdgcn_s_setprio(1);
    #pragma unroll
    for (int m = 0; m < 4; ++m)
      #pragma unroll
      for (int n = 2; n < 4; ++n)
        #pragma unroll
        for (int ks = 0; ks < 2; ++ks)
          acc[m + 4][n] = MFMA(af[m][ks], bfr[n][ks], acc[m + 4][n]);
    __builtin_amdgcn_s_setprio(0);

    __syncthreads();
  }

  int r0 = gp * 4;
  #pragma unroll
  for (int m = 0; m < 8; ++m) {
    #pragma unroll
    for (int n = 0; n < 4; ++n) {
      int col = n0 + wc * 64 + n * 16 + cl;
      #pragma unroll
      for (int j = 0; j < 4; ++j) {
        int row = m0 + wr * 128 + m * 16 + r0 + j;
        float v = acc[m][n][j];
        if (EPI == 1) v += R[(size_t)row * ldc + col];
        if (EPI == 2) v = fmaxf(v, 0.f);
        if (WF32) C[(size_t)row * ldc + col] = v;
        if (WB16) Cb[(size_t)row * ldc + col] = f2bf(v);
      }
    }
  }
}

// ---------------- fused causal attention, bf16 qkv in, bf16 out
#define LSTR 72
__global__ __launch_bounds__(256) void attn_kernel(const u16* __restrict__ qkv,
                                                   u16* __restrict__ outb) {
  __shared__ u16 Ksm[64 * LSTR];
  __shared__ u16 Vsm[64 * LSTR];   // transposed: [d][k]
  __shared__ u16 Psm[64 * LSTR];
  int qb = blockIdx.x, h = blockIdx.y, b = blockIdx.z;
  int tid = threadIdx.x;
  int lane = tid & 63, wave = tid >> 6;
  int cl = lane & 15, gp = lane >> 4;

  const u16* base = qkv + (size_t)b * SEQLEN * (3 * HIDDEN);

  int qrow_a = qb * 64 + wave * 16 + cl;
  bf16x8 qf[2];
  {
    const u16* qp = base + (size_t)qrow_a * (3 * HIDDEN) + h * HDIM;
    qf[0] = *(const bf16x8*)(qp + gp * 8);
    qf[1] = *(const bf16x8*)(qp + 32 + gp * 8);
  }

  float mrow[4], lrow[4];
  f32x4 oacc[4] = {};
  #pragma unroll
  for (int j = 0; j < 4; ++j) { mrow[j] = -INFINITY; lrow[j] = 0.f; }

  for (int t = 0; t <= qb; ++t) {
    #pragma unroll
    for (int it = 0; it < 4; ++it) {
      int idx = it * 256 + tid;
      int row = idx >> 4;
      int c4 = (idx & 15) * 4;
      const u16* kp = base + (size_t)(t * 64 + row) * (3 * HIDDEN) + HIDDEN + h * HDIM + c4;
      const u16* vp = base + (size_t)(t * 64 + row) * (3 * HIDDEN) + 2 * HIDDEN + h * HDIM + c4;
      *(uint2*)&Ksm[row * LSTR + c4] = *(const uint2*)kp;
      ushort4 vv = *(const ushort4*)vp;
      Vsm[(c4 + 0) * LSTR + row] = vv.x;
      Vsm[(c4 + 1) * LSTR + row] = vv.y;
      Vsm[(c4 + 2) * LSTR + row] = vv.z;
      Vsm[(c4 + 3) * LSTR + row] = vv.w;
    }
    __syncthreads();

    f32x4 sfr[4];
    #pragma unroll
    for (int n = 0; n < 4; ++n) {
      f32x4 z = {};
      #pragma unroll
      for (int ks = 0; ks < 2; ++ks) {
        int ko = ks * 32 + gp * 8;
        bf16x8 kf = *(const bf16x8*)&Ksm[(n * 16 + cl) * LSTR + ko];
        z = MFMA(qf[ks], kf, z);
      }
      sfr[n] = z;
    }
    #pragma unroll
    for (int n = 0; n < 4; ++n)
      #pragma unroll
      for (int j = 0; j < 4; ++j) {
        int qg = qb * 64 + wave * 16 + gp * 4 + j;
        int kg = t * 64 + n * 16 + cl;
        float sv = sfr[n][j] * 0.03125f;
        sfr[n][j] = (kg <= qg) ? sv : -1e30f;
      }
    float so[4];
    #pragma unroll
    for (int j = 0; j < 4; ++j) {
      float tm = fmaxf(fmaxf(sfr[0][j], sfr[1][j]), fmaxf(sfr[2][j], sfr[3][j]));
      tm = fmaxf(tm, __shfl_xor(tm, 1));
      tm = fmaxf(tm, __shfl_xor(tm, 2));
      tm = fmaxf(tm, __shfl_xor(tm, 4));
      tm = fmaxf(tm, __shfl_xor(tm, 8));
      float mn = fmaxf(mrow[j], tm);
      so[j] = expf(mrow[j] - mn);
      mrow[j] = mn;
      float ts = 0.f;
      #pragma unroll
      for (int n = 0; n < 4; ++n) {
        float p = expf(sfr[n][j] - mn);
        sfr[n][j] = p;
        ts += p;
      }
      ts += __shfl_xor(ts, 1); ts += __shfl_xor(ts, 2);
      ts += __shfl_xor(ts, 4); ts += __shfl_xor(ts, 8);
      lrow[j] = lrow[j] * so[j] + ts;
    }
    #pragma unroll
    for (int n = 0; n < 4; ++n)
      #pragma unroll
      for (int j = 0; j < 4; ++j)
        oacc[n][j] *= so[j];
    #pragma unroll
    for (int n = 0; n < 4; ++n)
      #pragma unroll
      for (int j = 0; j < 4; ++j)
        Psm[(wave * 16 + gp * 4 + j) * LSTR + n * 16 + cl] = f2bf(sfr[n][j]);
    __syncthreads();
    #pragma unroll
    for (int n = 0; n < 4; ++n) {
      #pragma unroll
      for (int ks = 0; ks < 2; ++ks) {
        int ko = ks * 32 + gp * 8;
        bf16x8 pa = *(const bf16x8*)&Psm[(wave * 16 + cl) * LSTR + ko];
        bf16x8 vb = *(const bf16x8*)&Vsm[(n * 16 + cl) * LSTR + ko];
        oacc[n] = MFMA(pa, vb, oacc[n]);
      }
    }
    __syncthreads();
  }
  #pragma unroll
  for (int n = 0; n < 4; ++n)
    #pragma unroll
    for (int j = 0; j < 4; ++j) {
      int qg = qb * 64 + wave * 16 + gp * 4 + j;
      int d = n * 16 + cl;
      outb[(size_t)(b * SEQLEN + qg) * HIDDEN + h * HDIM + d] = f2bf(oacc[n][j] / lrow[j]);
    }
}

extern "C" void kernel_launch(void* const* d_in, const int* in_sizes, int n_in,
                              void* d_out, int out_size, void* d_ws, size_t ws_size,
                              hipStream_t stream) {
  const int*   ids    = (const int*)d_in[0];
  const float* W_word = (const float*)d_in[1];
  const float* W_pos  = (const float*)d_in[2];
  const float* Wq     = (const float*)d_in[3];
  const float* Wk     = (const float*)d_in[4];
  const float* Wv     = (const float*)d_in[5];
  const float* Wo     = (const float*)d_in[6];
  const float* W1     = (const float*)d_in[7];
  const float* W2     = (const float*)d_in[8];
  const float* W_eh   = (const float*)d_in[9];
  const float* W_he   = (const float*)d_in[10];
  const float* W_lm   = (const float*)d_in[11];
  float* out = (float*)d_out;
  char*  ob  = (char*)d_out;
  char*  wb  = (char*)d_ws;

  const size_t MB = 1024 * 1024;
  float* h1    = (float*)(ob + 0 * MB);    // [4096,1024] f32
  float* h2    = (float*)(ob + 16 * MB);   // [4096,1024] f32
  u16*   h0b   = (u16*)(ob + 32 * MB);     // [4096,512]
  u16*   h1b   = (u16*)(ob + 36 * MB);     // [4096,1024]
  u16*   qkvb  = (u16*)(ob + 44 * MB);     // [4096,3072]
  u16*   attnb = (u16*)(ob + 68 * MB);     // [4096,1024]
  u16*   h2b   = (u16*)(ob + 76 * MB);     // [4096,1024]
  u16*   xb    = (u16*)(ob + 84 * MB);     // [4096,4096]
  u16*   h3b   = (u16*)(ob + 116 * MB);    // [4096,1024]
  u16*   Wqkv_b= (u16*)(ob + 124 * MB);    // [3072,1024] 6MB contiguous
  u16*   Wo_b  = (u16*)(ob + 130 * MB);
  u16*   W1_b  = (u16*)(ob + 132 * MB);    // 8MB
  u16*   W2_b  = (u16*)(ob + 140 * MB);    // 8MB
  u16*   Weh_b = (u16*)(ob + 148 * MB);
  u16*   Whe_b = (u16*)(ob + 149 * MB);
  u16*   he_b  = (u16*)(wb + 0);           // [4096,512] in d_ws
  u16*   Wlm_b = (u16*)(wb + 4 * MB);      // [32000,512] 32MB in d_ws
  bool big_ws = ws_size >= 36 * MB;

  cvt_kernel<<<dim3(1024), 256, 0, stream>>>(Wq, Wqkv_b + 0 * 1024 * 1024);
  cvt_kernel<<<dim3(1024), 256, 0, stream>>>(Wk, Wqkv_b + 1 * 1024 * 1024);
  cvt_kernel<<<dim3(1024), 256, 0, stream>>>(Wv, Wqkv_b + 2 * 1024 * 1024);
  cvt_kernel<<<dim3(1024), 256, 0, stream>>>(Wo, Wo_b);
  cvt_kernel<<<dim3(4096), 256, 0, stream>>>(W1, W1_b);
  cvt_kernel<<<dim3(4096), 256, 0, stream>>>(W2, W2_b);
  cvt_kernel<<<dim3(512),  256, 0, stream>>>(W_eh, Weh_b);
  cvt_kernel<<<dim3(512),  256, 0, stream>>>(W_he, Whe_b);
  if (big_ws)
    cvt_kernel<<<dim3(16000), 256, 0, stream>>>(W_lm, Wlm_b);

  embed_kernel<<<dim3(ROWS), 128, 0, stream>>>(ids, W_word, W_pos, h0b);

  // h1 = h0 @ W_eh.T  (f32 + bf16)
  gemm128<0, true, true, false, false><<<dim3(32, 8), 256, 0, stream>>>(
      h0b, Weh_b, nullptr, h1, h1b, nullptr, 512, HIDDEN);
  // qkv = h1 @ Wqkv.T  (fused, N=3072)
  gemm128<0, false, true, false, false><<<dim3(32, 24), 256, 0, stream>>>(
      h1b, Wqkv_b, nullptr, nullptr, qkvb, nullptr, 1024, 3 * HIDDEN);
  // attention
  attn_kernel<<<dim3(16, 16, 4), 256, 0, stream>>>(qkvb, attnb);
  // h2 = h1 + attn @ Wo.T  (f32 + bf16)
  gemm128<1, true, true, false, false><<<dim3(32, 8), 256, 0, stream>>>(
      attnb, Wo_b, nullptr, h2, h2b, h1, 1024, HIDDEN);
  // x = relu(h2 @ W1.T)  (256² tile, bf16 out)
  gemm256<2, false, true, false><<<dim3(16, 16), 512, 0, stream>>>(
      h2b, W1_b, nullptr, xb, nullptr, 1024, 4 * HIDDEN);
  // h3 = h2 + x @ W2.T  (bf16 out, f32 residual)
  gemm128<1, false, true, false, false><<<dim3(32, 8), 256, 0, stream>>>(
      xb, W2_b, nullptr, nullptr, h3b, h2, 4096, HIDDEN);
  // he = h3 @ W_he.T
  gemm128<0, false, true, false, false><<<dim3(32, 4), 256, 0, stream>>>(
      h3b, Whe_b, nullptr, nullptr, he_b, nullptr, 1024, EMBED);
  // logits = he @ W_lm.T  (entire d_out)
  if (big_ws)
    gemm256<0, true, false, true><<<dim3(16, 125), 512, 0, stream>>>(
        he_b, Wlm_b, out, nullptr, nullptr, 512, VOCAB);
  else
    gemm128<0, true, false, true, true><<<dim3(32, 250), 256, 0, stream>>>(
        he_b, nullptr, W_lm, out, nullptr, nullptr, 512, VOCAB);
}

// Round 5
// 543.509 us; speedup vs baseline: 2.5081x; 1.0771x over previous
//
#include <hip/hip_runtime.h>
#include <hip/hip_bf16.h>

#define HIDDEN 1024
#define NHEAD 16
#define HDIM 64
#define VOCAB 32000
#define SEQLEN 1024
#define EMBED 512
#define BATCH 4
#define ROWS (BATCH*SEQLEN)   // 4096

typedef __bf16 bf16x8 __attribute__((ext_vector_type(8)));
typedef float f32x4 __attribute__((ext_vector_type(4)));
typedef unsigned short u16;

#define MFMA(a_, b_, c_) __builtin_amdgcn_mfma_f32_16x16x32_bf16(a_, b_, c_, 0, 0, 0)

__device__ __forceinline__ u16 f2bf(float f) {
  unsigned u = __builtin_bit_cast(unsigned, f);
  u = u + 0x7FFFu + ((u >> 16) & 1u);
  return (u16)(u >> 16);
}

// async global->LDS, 16B/lane; LDS dest = wave-uniform base + lane*16 (global src per-lane)
#define GLDS(g_, l_) __builtin_amdgcn_global_load_lds( \
    (const __attribute__((address_space(1))) void*)(g_), \
    (__attribute__((address_space(3))) void*)(l_), 16, 0, 0)

// ---------------- merged f32 -> bf16 conversion for the 8 small weights
struct Cvt8 { const float* src[8]; u16* dst[8]; };
// blocks: [0,4096)=Wq/Wk/Wv/Wo (1024 ea), [4096,8192)=W1, [8192,12288)=W2,
//         [12288,12800)=Weh, [12800,13312)=Whe
__global__ void cvt8_kernel(Cvt8 cc) {
  int b = blockIdx.x;
  int seg, off;
  if (b < 4096)        { seg = b >> 10; off = b & 1023; }
  else if (b < 8192)   { seg = 4; off = b - 4096; }
  else if (b < 12288)  { seg = 5; off = b - 8192; }
  else if (b < 12800)  { seg = 6; off = b - 12288; }
  else                 { seg = 7; off = b - 12800; }
  size_t i = ((size_t)off * 256 + threadIdx.x) * 4;
  float4 v = *(const float4*)(cc.src[seg] + i);
  unsigned a = f2bf(v.x) | ((unsigned)f2bf(v.y) << 16);
  unsigned d = f2bf(v.z) | ((unsigned)f2bf(v.w) << 16);
  *(uint2*)(cc.dst[seg] + i) = make_uint2(a, d);
}

__global__ void cvt_kernel(const float* __restrict__ in, u16* __restrict__ out) {
  size_t i = ((size_t)blockIdx.x * 256 + threadIdx.x) * 4;
  float4 v = *(const float4*)(in + i);
  unsigned a = f2bf(v.x) | ((unsigned)f2bf(v.y) << 16);
  unsigned b = f2bf(v.z) | ((unsigned)f2bf(v.w) << 16);
  *(uint2*)(out + i) = make_uint2(a, b);
}

// ---------------- embedding -> bf16
__global__ void embed_kernel(const int* __restrict__ ids,
                             const float* __restrict__ W_word,
                             const float* __restrict__ W_pos,
                             u16* __restrict__ out) {
  int row = blockIdx.x;
  int s = row & (SEQLEN - 1);
  int id = ids[row];
  int e = threadIdx.x * 4;
  float4 a = *(const float4*)(W_word + (size_t)id * EMBED + e);
  float4 b = *(const float4*)(W_pos + (size_t)s * EMBED + e);
  unsigned lo = f2bf(a.x + b.x) | ((unsigned)f2bf(a.y + b.y) << 16);
  unsigned hi = f2bf(a.z + b.z) | ((unsigned)f2bf(a.w + b.w) << 16);
  *(uint2*)(out + (size_t)row * EMBED + e) = make_uint2(lo, hi);
}

// ======================================================================
// 128x128 GEMM, 4 waves, dbuf LDS, rotation-swizzled, 1 barrier/K-tile.
template<int EPI, bool WF32, bool WB16, bool BF32, bool SWZ, bool NT = false>
__global__ __launch_bounds__(256, 2) void gemm128(
    const u16* __restrict__ A, const u16* __restrict__ Bb,
    const float* __restrict__ Bf,
    float* __restrict__ C, u16* __restrict__ Cb,
    const float* __restrict__ R, int K, int ldc)
{
  __shared__ u16 As[2][128 * 64];
  __shared__ u16 Bs[2][128 * 64];
  int tid = threadIdx.x;
  int lane = tid & 63, wave = tid >> 6;
  int wr = wave >> 1, wc = wave & 1;
  int cl = lane & 15, gp = (lane >> 4) & 3;

  int bx = blockIdx.x, by = blockIdx.y;
  if (SWZ) {
    int nwg = gridDim.x * gridDim.y;
    int flat = by * gridDim.x + bx;
    int cpx = nwg >> 3;
    int swz = (flat & 7) * cpx + (flat >> 3);
    bx = swz % gridDim.x; by = swz / gridDim.x;
  }
  int m0 = bx * 128, n0 = by * 128;

  int srow8 = lane >> 3;
  int scol = (((lane & 7) - srow8) & 7) * 8;
  int pos0 = ((gp + cl) & 7) * 8;
  int pos1 = ((gp + cl + 4) & 7) * 8;

  f32x4 acc[4][4] = {};
  int nk = K >> 6;

  #pragma unroll
  for (int i = 0; i < 4; ++i) {
    int c = i * 4 + wave;
    int row = c * 8 + srow8;
    GLDS(A + (size_t)(m0 + row) * K + scol, &As[0][c * 512]);
    if (!BF32) GLDS(Bb + (size_t)(n0 + row) * K + scol, &Bs[0][c * 512]);
  }
  if (BF32) {
    #pragma unroll
    for (int it = 0; it < 4; ++it) {
      int idx = it * 256 + tid;
      int row = idx >> 3, p = idx & 7;
      int gc = (p - row) & 7;
      const float* src = Bf + (size_t)(n0 + row) * K + gc * 8;
      float4 v0 = *(const float4*)src, v1 = *(const float4*)(src + 4);
      union { bf16x8 v; u16 s[8]; } u;
      u.s[0]=f2bf(v0.x); u.s[1]=f2bf(v0.y); u.s[2]=f2bf(v0.z); u.s[3]=f2bf(v0.w);
      u.s[4]=f2bf(v1.x); u.s[5]=f2bf(v1.y); u.s[6]=f2bf(v1.z); u.s[7]=f2bf(v1.w);
      *(bf16x8*)&Bs[0][row * 64 + p * 8] = u.v;
    }
  }
  __syncthreads();

  for (int kt = 0; kt < nk; ++kt) {
    int buf = kt & 1;
    int kb = (kt + 1) << 6;
    bool more = kt + 1 < nk;
    bf16x8 af[2][2], bfr[4][2];

    if (more) {
      #pragma unroll
      for (int i = 0; i < 4; ++i) {
        int c = i * 4 + wave;
        GLDS(A + (size_t)(m0 + c * 8 + srow8) * K + kb + scol, &As[buf ^ 1][c * 512]);
      }
    }
    #pragma unroll
    for (int n = 0; n < 4; ++n) {
      int r = (wc * 64 + n * 16 + cl) * 64;
      bfr[n][0] = *(const bf16x8*)&Bs[buf][r + pos0];
      bfr[n][1] = *(const bf16x8*)&Bs[buf][r + pos1];
    }
    #pragma unroll
    for (int m = 0; m < 2; ++m) {
      int r = (wr * 64 + m * 16 + cl) * 64;
      af[m][0] = *(const bf16x8*)&As[buf][r + pos0];
      af[m][1] = *(const bf16x8*)&As[buf][r + pos1];
    }
    __builtin_amdgcn_s_setprio(1);
    #pragma unroll
    for (int m = 0; m < 2; ++m)
      #pragma unroll
      for (int n = 0; n < 2; ++n)
        #pragma unroll
        for (int ks = 0; ks < 2; ++ks)
          acc[m][n] = MFMA(af[m][ks], bfr[n][ks], acc[m][n]);
    __builtin_amdgcn_s_setprio(0);

    if (more) {
      if (!BF32) {
        #pragma unroll
        for (int i = 0; i < 4; ++i) {
          int c = i * 4 + wave;
          GLDS(Bb + (size_t)(n0 + c * 8 + srow8) * K + kb + scol, &Bs[buf ^ 1][c * 512]);
        }
      } else {
        #pragma unroll
        for (int it = 0; it < 4; ++it) {
          int idx = it * 256 + tid;
          int row = idx >> 3, p = idx & 7;
          int gc = (p - row) & 7;
          const float* src = Bf + (size_t)(n0 + row) * K + kb + gc * 8;
          float4 v0 = *(const float4*)src, v1 = *(const float4*)(src + 4);
          union { bf16x8 v; u16 s[8]; } u;
          u.s[0]=f2bf(v0.x); u.s[1]=f2bf(v0.y); u.s[2]=f2bf(v0.z); u.s[3]=f2bf(v0.w);
          u.s[4]=f2bf(v1.x); u.s[5]=f2bf(v1.y); u.s[6]=f2bf(v1.z); u.s[7]=f2bf(v1.w);
          *(bf16x8*)&Bs[buf ^ 1][row * 64 + p * 8] = u.v;
        }
      }
    }
    __builtin_amdgcn_s_setprio(1);
    #pragma unroll
    for (int m = 0; m < 2; ++m)
      #pragma unroll
      for (int n = 2; n < 4; ++n)
        #pragma unroll
        for (int ks = 0; ks < 2; ++ks)
          acc[m][n] = MFMA(af[m][ks], bfr[n][ks], acc[m][n]);
    __builtin_amdgcn_s_setprio(0);

    #pragma unroll
    for (int m = 0; m < 2; ++m) {
      int r = (wr * 64 + (m + 2) * 16 + cl) * 64;
      af[m][0] = *(const bf16x8*)&As[buf][r + pos0];
      af[m][1] = *(const bf16x8*)&As[buf][r + pos1];
    }
    __builtin_amdgcn_s_setprio(1);
    #pragma unroll
    for (int m = 0; m < 2; ++m)
      #pragma unroll
      for (int n = 0; n < 2; ++n)
        #pragma unroll
        for (int ks = 0; ks < 2; ++ks)
          acc[m + 2][n] = MFMA(af[m][ks], bfr[n][ks], acc[m + 2][n]);
    __builtin_amdgcn_s_setprio(0);

    __builtin_amdgcn_s_setprio(1);
    #pragma unroll
    for (int m = 0; m < 2; ++m)
      #pragma unroll
      for (int n = 2; n < 4; ++n)
        #pragma unroll
        for (int ks = 0; ks < 2; ++ks)
          acc[m + 2][n] = MFMA(af[m][ks], bfr[n][ks], acc[m + 2][n]);
    __builtin_amdgcn_s_setprio(0);

    __syncthreads();
  }

  int r0 = gp * 4;
  #pragma unroll
  for (int m = 0; m < 4; ++m) {
    #pragma unroll
    for (int n = 0; n < 4; ++n) {
      int col = n0 + wc * 64 + n * 16 + cl;
      #pragma unroll
      for (int j = 0; j < 4; ++j) {
        int row = m0 + wr * 64 + m * 16 + r0 + j;
        float v = acc[m][n][j];
        if (EPI == 1) v += R[(size_t)row * ldc + col];
        if (EPI == 2) v = fmaxf(v, 0.f);
        if (WF32) {
          if (NT) __builtin_nontemporal_store(v, &C[(size_t)row * ldc + col]);
          else C[(size_t)row * ldc + col] = v;
        }
        if (WB16) Cb[(size_t)row * ldc + col] = f2bf(v);
      }
    }
  }
}

// ======================================================================
// 256x256 GEMM, 8 waves (2Mx4N), 128KB dbuf LDS, rotation-swizzled.
template<int EPI, bool WF32, bool WB16, bool SWZ, bool NT = false>
__global__ __launch_bounds__(512) void gemm256(
    const u16* __restrict__ A, const u16* __restrict__ B,
    float* __restrict__ C, u16* __restrict__ Cb,
    const float* __restrict__ R, int K, int ldc)
{
  __shared__ u16 As[2][256 * 64];
  __shared__ u16 Bs[2][256 * 64];
  int tid = threadIdx.x;
  int lane = tid & 63, wave = tid >> 6;
  int wr = wave >> 2, wc = wave & 3;
  int cl = lane & 15, gp = (lane >> 4) & 3;

  int bx = blockIdx.x, by = blockIdx.y;
  if (SWZ) {
    int nwg = gridDim.x * gridDim.y;
    int flat = by * gridDim.x + bx;
    int cpx = nwg >> 3;
    int swz = (flat & 7) * cpx + (flat >> 3);
    bx = swz % gridDim.x; by = swz / gridDim.x;
  }
  int m0 = bx * 256, n0 = by * 256;

  int srow8 = lane >> 3;
  int scol = (((lane & 7) - srow8) & 7) * 8;
  int pos0 = ((gp + cl) & 7) * 8;
  int pos1 = ((gp + cl + 4) & 7) * 8;

  f32x4 acc[8][4] = {};
  int nk = K >> 6;

  #pragma unroll
  for (int i = 0; i < 4; ++i) {
    int c = i * 8 + wave;
    int row = c * 8 + srow8;
    GLDS(A + (size_t)(m0 + row) * K + scol, &As[0][c * 512]);
    GLDS(B + (size_t)(n0 + row) * K + scol, &Bs[0][c * 512]);
  }
  __syncthreads();

  for (int kt = 0; kt < nk; ++kt) {
    int buf = kt & 1;
    int kb = (kt + 1) << 6;
    bool more = kt + 1 < nk;
    bf16x8 af[4][2], bfr[4][2];

    if (more) {
      #pragma unroll
      for (int i = 0; i < 4; ++i) {
        int c = i * 8 + wave;
        GLDS(A + (size_t)(m0 + c * 8 + srow8) * K + kb + scol, &As[buf ^ 1][c * 512]);
      }
    }
    #pragma unroll
    for (int n = 0; n < 4; ++n) {
      int r = (wc * 64 + n * 16 + cl) * 64;
      bfr[n][0] = *(const bf16x8*)&Bs[buf][r + pos0];
      bfr[n][1] = *(const bf16x8*)&Bs[buf][r + pos1];
    }
    #pragma unroll
    for (int m = 0; m < 4; ++m) {
      int r = (wr * 128 + m * 16 + cl) * 64;
      af[m][0] = *(const bf16x8*)&As[buf][r + pos0];
      af[m][1] = *(const bf16x8*)&As[buf][r + pos1];
    }
    __builtin_amdgcn_s_setprio(1);
    #pragma unroll
    for (int m = 0; m < 4; ++m)
      #pragma unroll
      for (int n = 0; n < 2; ++n)
        #pragma unroll
        for (int ks = 0; ks < 2; ++ks)
          acc[m][n] = MFMA(af[m][ks], bfr[n][ks], acc[m][n]);
    __builtin_amdgcn_s_setprio(0);

    if (more) {
      #pragma unroll
      for (int i = 0; i < 4; ++i) {
        int c = i * 8 + wave;
        GLDS(B + (size_t)(n0 + c * 8 + srow8) * K + kb + scol, &Bs[buf ^ 1][c * 512]);
      }
    }
    __builtin_amdgcn_s_setprio(1);
    #pragma unroll
    for (int m = 0; m < 4; ++m)
      #pragma unroll
      for (int n = 2; n < 4; ++n)
        #pragma unroll
        for (int ks = 0; ks < 2; ++ks)
          acc[m][n] = MFMA(af[m][ks], bfr[n][ks], acc[m][n]);
    __builtin_amdgcn_s_setprio(0);

    #pragma unroll
    for (int m = 0; m < 4; ++m) {
      int r = (wr * 128 + (m + 4) * 16 + cl) * 64;
      af[m][0] = *(const bf16x8*)&As[buf][r + pos0];
      af[m][1] = *(const bf16x8*)&As[buf][r + pos1];
    }
    __builtin_amdgcn_s_setprio(1);
    #pragma unroll
    for (int m = 0; m < 4; ++m)
      #pragma unroll
      for (int n = 0; n < 2; ++n)
        #pragma unroll
        for (int ks = 0; ks < 2; ++ks)
          acc[m + 4][n] = MFMA(af[m][ks], bfr[n][ks], acc[m + 4][n]);
    __builtin_amdgcn_s_setprio(0);

    __builtin_amdgcn_s_setprio(1);
    #pragma unroll
    for (int m = 0; m < 4; ++m)
      #pragma unroll
      for (int n = 2; n < 4; ++n)
        #pragma unroll
        for (int ks = 0; ks < 2; ++ks)
          acc[m + 4][n] = MFMA(af[m][ks], bfr[n][ks], acc[m + 4][n]);
    __builtin_amdgcn_s_setprio(0);

    __syncthreads();
  }

  int r0 = gp * 4;
  #pragma unroll
  for (int m = 0; m < 8; ++m) {
    #pragma unroll
    for (int n = 0; n < 4; ++n) {
      int col = n0 + wc * 64 + n * 16 + cl;
      #pragma unroll
      for (int j = 0; j < 4; ++j) {
        int row = m0 + wr * 128 + m * 16 + r0 + j;
        float v = acc[m][n][j];
        if (EPI == 1) v += R[(size_t)row * ldc + col];
        if (EPI == 2) v = fmaxf(v, 0.f);
        if (WF32) {
          if (NT) __builtin_nontemporal_store(v, &C[(size_t)row * ldc + col]);
          else C[(size_t)row * ldc + col] = v;
        }
        if (WB16) Cb[(size_t)row * ldc + col] = f2bf(v);
      }
    }
  }
}

// ---------------- fused causal attention v2: dbuf K/V, GLDS K, 1 barrier/tile
#define LSTR 72
__global__ __launch_bounds__(256) void attn_kernel(const u16* __restrict__ qkv,
                                                   u16* __restrict__ outb) {
  __shared__ u16 Ksm[2][64 * 64];   // rotation-swizzled (GLDS-staged)
  __shared__ u16 Vsm[2][64 * LSTR]; // transposed [d][k], padded
  __shared__ u16 Psm[64 * LSTR];    // per-wave P, intra-wave round-trip
  int qb = blockIdx.x, h = blockIdx.y, b = blockIdx.z;
  int tid = threadIdx.x;
  int lane = tid & 63, wave = tid >> 6;
  int cl = lane & 15, gp = lane >> 4;
  int srow8 = lane >> 3;
  int gsrc = (((lane & 7) - srow8) & 7) * 8;   // rotated source elem offset

  const u16* base = qkv + (size_t)b * SEQLEN * (3 * HIDDEN);

  int qrow_a = qb * 64 + wave * 16 + cl;
  const u16* qp = base + (size_t)qrow_a * (3 * HIDDEN) + h * HDIM;
  bf16x8 qf0 = *(const bf16x8*)(qp + gp * 8);
  bf16x8 qf1 = *(const bf16x8*)(qp + 32 + gp * 8);

  ushort4 vr[4];

  auto stageK = [&](int t, int bb) {
    #pragma unroll
    for (int i = 0; i < 2; ++i) {
      int c = wave * 2 + i;
      int row = c * 8 + srow8;
      GLDS(base + (size_t)(t * 64 + row) * (3 * HIDDEN) + HIDDEN + h * HDIM + gsrc,
           &Ksm[bb][c * 512]);
    }
  };
  auto loadV = [&](int t) {
    #pragma unroll
    for (int it = 0; it < 4; ++it) {
      int idx = it * 256 + tid;
      int row = idx >> 4, c4 = (idx & 15) * 4;
      vr[it] = *(const ushort4*)(base + (size_t)(t * 64 + row) * (3 * HIDDEN) +
                                 2 * HIDDEN + h * HDIM + c4);
    }
  };
  auto writeV = [&](int bb) {
    #pragma unroll
    for (int it = 0; it < 4; ++it) {
      int idx = it * 256 + tid;
      int row = idx >> 4, c4 = (idx & 15) * 4;
      Vsm[bb][(c4 + 0) * LSTR + row] = vr[it].x;
      Vsm[bb][(c4 + 1) * LSTR + row] = vr[it].y;
      Vsm[bb][(c4 + 2) * LSTR + row] = vr[it].z;
      Vsm[bb][(c4 + 3) * LSTR + row] = vr[it].w;
    }
  };

  stageK(0, 0);
  loadV(0);
  writeV(0);
  __syncthreads();   // drains GLDS vmcnt + LDS writes

  float mrow[4], lrow[4];
  f32x4 oacc[4] = {};
  #pragma unroll
  for (int j = 0; j < 4; ++j) { mrow[j] = -INFINITY; lrow[j] = 0.f; }

  for (int t = 0; t <= qb; ++t) {
    int buf = t & 1;
    bool more = t < qb;
    if (more) { stageK(t + 1, buf ^ 1); loadV(t + 1); }   // issue early (T14)

    // S = Q K^T
    f32x4 sfr[4];
    __builtin_amdgcn_s_setprio(1);
    #pragma unroll
    for (int n = 0; n < 4; ++n) {
      f32x4 z = {};
      bf16x8 kf0 = *(const bf16x8*)&Ksm[buf][(n * 16 + cl) * 64 + ((gp + cl) & 7) * 8];
      bf16x8 kf1 = *(const bf16x8*)&Ksm[buf][(n * 16 + cl) * 64 + ((gp + cl + 4) & 7) * 8];
      z = MFMA(qf0, kf0, z);
      z = MFMA(qf1, kf1, z);
      sfr[n] = z;
    }
    __builtin_amdgcn_s_setprio(0);

    // mask + scale
    #pragma unroll
    for (int n = 0; n < 4; ++n)
      #pragma unroll
      for (int j = 0; j < 4; ++j) {
        int qg = qb * 64 + wave * 16 + gp * 4 + j;
        int kg = t * 64 + n * 16 + cl;
        float sv = sfr[n][j] * 0.03125f;
        sfr[n][j] = (kg <= qg) ? sv : -1e30f;
      }
    // online softmax (rows in 16-lane groups)
    float so[4];
    #pragma unroll
    for (int j = 0; j < 4; ++j) {
      float tm = fmaxf(fmaxf(sfr[0][j], sfr[1][j]), fmaxf(sfr[2][j], sfr[3][j]));
      tm = fmaxf(tm, __shfl_xor(tm, 1));
      tm = fmaxf(tm, __shfl_xor(tm, 2));
      tm = fmaxf(tm, __shfl_xor(tm, 4));
      tm = fmaxf(tm, __shfl_xor(tm, 8));
      float mn = fmaxf(mrow[j], tm);
      so[j] = __expf(mrow[j] - mn);
      mrow[j] = mn;
      float ts = 0.f;
      #pragma unroll
      for (int n = 0; n < 4; ++n) {
        float p = __expf(sfr[n][j] - mn);
        sfr[n][j] = p;
        ts += p;
      }
      ts += __shfl_xor(ts, 1); ts += __shfl_xor(ts, 2);
      ts += __shfl_xor(ts, 4); ts += __shfl_xor(ts, 8);
      lrow[j] = lrow[j] * so[j] + ts;
    }
    #pragma unroll
    for (int n = 0; n < 4; ++n)
      #pragma unroll
      for (int j = 0; j < 4; ++j)
        oacc[n][j] *= so[j];

    if (more) writeV(buf ^ 1);   // LDS write late, other buffer

    // P -> LDS (intra-wave rows only: write wave*16+gp*4+j, read wave*16+cl)
    #pragma unroll
    for (int n = 0; n < 4; ++n)
      #pragma unroll
      for (int j = 0; j < 4; ++j)
        Psm[(wave * 16 + gp * 4 + j) * LSTR + n * 16 + cl] = f2bf(sfr[n][j]);
    __builtin_amdgcn_sched_barrier(0);   // keep DS write->read order

    // O += P V
    bf16x8 pa0 = *(const bf16x8*)&Psm[(wave * 16 + cl) * LSTR + gp * 8];
    bf16x8 pa1 = *(const bf16x8*)&Psm[(wave * 16 + cl) * LSTR + 32 + gp * 8];
    __builtin_amdgcn_s_setprio(1);
    #pragma unroll
    for (int n = 0; n < 4; ++n) {
      bf16x8 vb0 = *(const bf16x8*)&Vsm[buf][(n * 16 + cl) * LSTR + gp * 8];
      bf16x8 vb1 = *(const bf16x8*)&Vsm[buf][(n * 16 + cl) * LSTR + 32 + gp * 8];
      oacc[n] = MFMA(pa0, vb0, oacc[n]);
      oacc[n] = MFMA(pa1, vb1, oacc[n]);
    }
    __builtin_amdgcn_s_setprio(0);

    __syncthreads();   // one barrier per tile
  }

  #pragma unroll
  for (int n = 0; n < 4; ++n)
    #pragma unroll
    for (int j = 0; j < 4; ++j) {
      int qg = qb * 64 + wave * 16 + gp * 4 + j;
      int d = n * 16 + cl;
      outb[(size_t)(b * SEQLEN + qg) * HIDDEN + h * HDIM + d] = f2bf(oacc[n][j] / lrow[j]);
    }
}

extern "C" void kernel_launch(void* const* d_in, const int* in_sizes, int n_in,
                              void* d_out, int out_size, void* d_ws, size_t ws_size,
                              hipStream_t stream) {
  const int*   ids    = (const int*)d_in[0];
  const float* W_word = (const float*)d_in[1];
  const float* W_pos  = (const float*)d_in[2];
  const float* Wq     = (const float*)d_in[3];
  const float* Wk     = (const float*)d_in[4];
  const float* Wv     = (const float*)d_in[5];
  const float* Wo     = (const float*)d_in[6];
  const float* W1     = (const float*)d_in[7];
  const float* W2     = (const float*)d_in[8];
  const float* W_eh   = (const float*)d_in[9];
  const float* W_he   = (const float*)d_in[10];
  const float* W_lm   = (const float*)d_in[11];
  float* out = (float*)d_out;
  char*  ob  = (char*)d_out;
  char*  wb  = (char*)d_ws;

  const size_t MB = 1024 * 1024;
  float* h1    = (float*)(ob + 0 * MB);
  float* h2    = (float*)(ob + 16 * MB);
  u16*   h0b   = (u16*)(ob + 32 * MB);
  u16*   h1b   = (u16*)(ob + 36 * MB);
  u16*   qkvb  = (u16*)(ob + 44 * MB);
  u16*   attnb = (u16*)(ob + 68 * MB);
  u16*   h2b   = (u16*)(ob + 76 * MB);
  u16*   xb    = (u16*)(ob + 84 * MB);
  u16*   h3b   = (u16*)(ob + 116 * MB);
  u16*   Wqkv_b= (u16*)(ob + 124 * MB);
  u16*   Wo_b  = (u16*)(ob + 130 * MB);
  u16*   W1_b  = (u16*)(ob + 132 * MB);
  u16*   W2_b  = (u16*)(ob + 140 * MB);
  u16*   Weh_b = (u16*)(ob + 148 * MB);
  u16*   Whe_b = (u16*)(ob + 149 * MB);
  u16*   he_b  = (u16*)(wb + 0);
  u16*   Wlm_b = (u16*)(wb + 4 * MB);
  bool big_ws = ws_size >= 36 * MB;

  Cvt8 cc;
  cc.src[0] = Wq;  cc.dst[0] = Wqkv_b + 0 * 1024 * 1024;
  cc.src[1] = Wk;  cc.dst[1] = Wqkv_b + 1 * 1024 * 1024;
  cc.src[2] = Wv;  cc.dst[2] = Wqkv_b + 2 * 1024 * 1024;
  cc.src[3] = Wo;  cc.dst[3] = Wo_b;
  cc.src[4] = W1;  cc.dst[4] = W1_b;
  cc.src[5] = W2;  cc.dst[5] = W2_b;
  cc.src[6] = W_eh; cc.dst[6] = Weh_b;
  cc.src[7] = W_he; cc.dst[7] = Whe_b;
  cvt8_kernel<<<dim3(13312), 256, 0, stream>>>(cc);
  if (big_ws)
    cvt_kernel<<<dim3(16000), 256, 0, stream>>>(W_lm, Wlm_b);

  embed_kernel<<<dim3(ROWS), 128, 0, stream>>>(ids, W_word, W_pos, h0b);

  // h1 = h0 @ W_eh.T
  gemm128<0, true, true, false, false><<<dim3(32, 8), 256, 0, stream>>>(
      h0b, Weh_b, nullptr, h1, h1b, nullptr, 512, HIDDEN);
  // qkv = h1 @ Wqkv.T
  gemm128<0, false, true, false, false><<<dim3(32, 24), 256, 0, stream>>>(
      h1b, Wqkv_b, nullptr, nullptr, qkvb, nullptr, 1024, 3 * HIDDEN);
  // attention
  attn_kernel<<<dim3(16, 16, 4), 256, 0, stream>>>(qkvb, attnb);
  // h2 = h1 + attn @ Wo.T
  gemm128<1, true, true, false, false><<<dim3(32, 8), 256, 0, stream>>>(
      attnb, Wo_b, nullptr, h2, h2b, h1, 1024, HIDDEN);
  // x = relu(h2 @ W1.T)
  gemm256<2, false, true, false><<<dim3(16, 16), 512, 0, stream>>>(
      h2b, W1_b, nullptr, xb, nullptr, 1024, 4 * HIDDEN);
  // h3 = h2 + x @ W2.T
  gemm128<1, false, true, false, false><<<dim3(32, 8), 256, 0, stream>>>(
      xb, W2_b, nullptr, nullptr, h3b, h2, 4096, HIDDEN);
  // he = h3 @ W_he.T
  gemm128<0, false, true, false, false><<<dim3(32, 4), 256, 0, stream>>>(
      h3b, Whe_b, nullptr, nullptr, he_b, nullptr, 1024, EMBED);
  // logits = he @ W_lm.T  (nontemporal f32 stores)
  if (big_ws)
    gemm256<0, true, false, true, true><<<dim3(16, 125), 512, 0, stream>>>(
        he_b, Wlm_b, out, nullptr, nullptr, 512, VOCAB);
  else
    gemm128<0, true, false, true, true, true><<<dim3(32, 250), 256, 0, stream>>>(
        he_b, nullptr, W_lm, out, nullptr, nullptr, 512, VOCAB);
}

// Round 6
// 543.394 us; speedup vs baseline: 2.5087x; 1.0002x over previous
//
#include <hip/hip_runtime.h>
#include <hip/hip_bf16.h>

#define HIDDEN 1024
#define NHEAD 16
#define HDIM 64
#define VOCAB 32000
#define SEQLEN 1024
#define EMBED 512
#define BATCH 4
#define ROWS (BATCH*SEQLEN)   // 4096

typedef __bf16 bf16x8 __attribute__((ext_vector_type(8)));
typedef float f32x4 __attribute__((ext_vector_type(4)));
typedef unsigned short u16;

#define MFMA(a_, b_, c_) __builtin_amdgcn_mfma_f32_16x16x32_bf16(a_, b_, c_, 0, 0, 0)

// sync primitives for the counted-vmcnt dual-barrier K-loop
#define VMCNT4 asm volatile("s_waitcnt vmcnt(4)" ::: "memory")
#define VMCNT0 asm volatile("s_waitcnt vmcnt(0)" ::: "memory")
#define LGKM0  asm volatile("s_waitcnt lgkmcnt(0)" ::: "memory")
#define CFENCE asm volatile("" ::: "memory")
#define SBAR   __builtin_amdgcn_s_barrier()
#define SCHEDB __builtin_amdgcn_sched_barrier(0)

__device__ __forceinline__ u16 f2bf(float f) {
  unsigned u = __builtin_bit_cast(unsigned, f);
  u = u + 0x7FFFu + ((u >> 16) & 1u);
  return (u16)(u >> 16);
}

// async global->LDS, 16B/lane; LDS dest = wave-uniform base + lane*16 (global src per-lane)
#define GLDS(g_, l_) __builtin_amdgcn_global_load_lds( \
    (const __attribute__((address_space(1))) void*)(g_), \
    (__attribute__((address_space(3))) void*)(l_), 16, 0, 0)

// ---------------- merged f32 -> bf16 conversion for the 8 small weights
struct Cvt8 { const float* src[8]; u16* dst[8]; };
__global__ void cvt8_kernel(Cvt8 cc) {
  int b = blockIdx.x;
  int seg, off;
  if (b < 4096)        { seg = b >> 10; off = b & 1023; }
  else if (b < 8192)   { seg = 4; off = b - 4096; }
  else if (b < 12288)  { seg = 5; off = b - 8192; }
  else if (b < 12800)  { seg = 6; off = b - 12288; }
  else                 { seg = 7; off = b - 12800; }
  size_t i = ((size_t)off * 256 + threadIdx.x) * 4;
  float4 v = *(const float4*)(cc.src[seg] + i);
  unsigned a = f2bf(v.x) | ((unsigned)f2bf(v.y) << 16);
  unsigned d = f2bf(v.z) | ((unsigned)f2bf(v.w) << 16);
  *(uint2*)(cc.dst[seg] + i) = make_uint2(a, d);
}

__global__ void cvt_kernel(const float* __restrict__ in, u16* __restrict__ out) {
  size_t i = ((size_t)blockIdx.x * 256 + threadIdx.x) * 4;
  float4 v = *(const float4*)(in + i);
  unsigned a = f2bf(v.x) | ((unsigned)f2bf(v.y) << 16);
  unsigned b = f2bf(v.z) | ((unsigned)f2bf(v.w) << 16);
  *(uint2*)(out + i) = make_uint2(a, b);
}

// ---------------- embedding -> bf16
__global__ void embed_kernel(const int* __restrict__ ids,
                             const float* __restrict__ W_word,
                             const float* __restrict__ W_pos,
                             u16* __restrict__ out) {
  int row = blockIdx.x;
  int s = row & (SEQLEN - 1);
  int id = ids[row];
  int e = threadIdx.x * 4;
  float4 a = *(const float4*)(W_word + (size_t)id * EMBED + e);
  float4 b = *(const float4*)(W_pos + (size_t)s * EMBED + e);
  unsigned lo = f2bf(a.x + b.x) | ((unsigned)f2bf(a.y + b.y) << 16);
  unsigned hi = f2bf(a.z + b.z) | ((unsigned)f2bf(a.w + b.w) << 16);
  *(uint2*)(out + (size_t)row * EMBED + e) = make_uint2(lo, hi);
}

// ======================================================================
// 128x128 GEMM, 4 waves, dbuf LDS, rotation-swizzled, counted-vmcnt dual-barrier loop.
template<int EPI, bool WF32, bool WB16, bool BF32, bool SWZ, bool NT = false>
__global__ __launch_bounds__(256, 2) void gemm128(
    const u16* __restrict__ A, const u16* __restrict__ Bb,
    const float* __restrict__ Bf,
    float* __restrict__ C, u16* __restrict__ Cb,
    const float* __restrict__ R, int K, int ldc)
{
  __shared__ u16 As[2][128 * 64];
  __shared__ u16 Bs[2][128 * 64];
  int tid = threadIdx.x;
  int lane = tid & 63, wave = tid >> 6;
  int wr = wave >> 1, wc = wave & 1;
  int cl = lane & 15, gp = (lane >> 4) & 3;

  int bx = blockIdx.x, by = blockIdx.y;
  if (SWZ) {
    int nwg = gridDim.x * gridDim.y;
    int flat = by * gridDim.x + bx;
    int cpx = nwg >> 3;
    int swz = (flat & 7) * cpx + (flat >> 3);
    bx = swz % gridDim.x; by = swz / gridDim.x;
  }
  int m0 = bx * 128, n0 = by * 128;

  int srow8 = lane >> 3;
  int scol = (((lane & 7) - srow8) & 7) * 8;
  int pos0 = ((gp + cl) & 7) * 8;
  int pos1 = ((gp + cl + 4) & 7) * 8;

  f32x4 acc[4][4] = {};
  int nk = K >> 6;

  // prologue: tile 0 -> buf 0 (A first, then B: issue order matters for vmcnt math)
  #pragma unroll
  for (int i = 0; i < 4; ++i) {
    int c = i * 4 + wave;
    GLDS(A + (size_t)(m0 + c * 8 + srow8) * K + scol, &As[0][c * 512]);
  }
  if (!BF32) {
    #pragma unroll
    for (int i = 0; i < 4; ++i) {
      int c = i * 4 + wave;
      GLDS(Bb + (size_t)(n0 + c * 8 + srow8) * K + scol, &Bs[0][c * 512]);
    }
  } else {
    #pragma unroll
    for (int it = 0; it < 4; ++it) {
      int idx = it * 256 + tid;
      int row = idx >> 3, p = idx & 7;
      int gc = (p - row) & 7;
      const float* src = Bf + (size_t)(n0 + row) * K + gc * 8;
      float4 v0 = *(const float4*)src, v1 = *(const float4*)(src + 4);
      union { bf16x8 v; u16 s[8]; } u;
      u.s[0]=f2bf(v0.x); u.s[1]=f2bf(v0.y); u.s[2]=f2bf(v0.z); u.s[3]=f2bf(v0.w);
      u.s[4]=f2bf(v1.x); u.s[5]=f2bf(v1.y); u.s[6]=f2bf(v1.z); u.s[7]=f2bf(v1.w);
      *(bf16x8*)&Bs[0][row * 64 + p * 8] = u.v;
    }
  }

  for (int kt = 0; kt < nk; ++kt) {
    int buf = kt & 1;
    int kb = (kt + 1) << 6;
    bool more = kt + 1 < nk;

    // stage next-A (issued before the wait: stays in flight across the boundary)
    if (more) {
      #pragma unroll
      for (int i = 0; i < 4; ++i) {
        int c = i * 4 + wave;
        GLDS(A + (size_t)(m0 + c * 8 + srow8) * K + kb + scol, &As[buf ^ 1][c * 512]);
      }
    }
    if (BF32) { VMCNT0; } else if (more) { VMCNT4; } else { VMCNT0; }
    SCHEDB;
    SBAR;              // publish tile t (every wave's loads for t retired above)
    CFENCE; SCHEDB;

    bf16x8 af[4][2], bfv[4][2];
    #pragma unroll
    for (int n = 0; n < 4; ++n) {
      int r = (wc * 64 + n * 16 + cl) * 64;
      bfv[n][0] = *(const bf16x8*)&Bs[buf][r + pos0];
      bfv[n][1] = *(const bf16x8*)&Bs[buf][r + pos1];
    }
    #pragma unroll
    for (int m = 0; m < 4; ++m) {
      int r = (wr * 64 + m * 16 + cl) * 64;
      af[m][0] = *(const bf16x8*)&As[buf][r + pos0];
      af[m][1] = *(const bf16x8*)&As[buf][r + pos1];
    }

    __builtin_amdgcn_s_setprio(1);
    #pragma unroll
    for (int m = 0; m < 2; ++m)
      #pragma unroll
      for (int n = 0; n < 4; ++n)
        #pragma unroll
        for (int ks = 0; ks < 2; ++ks)
          acc[m][n] = MFMA(af[m][ks], bfv[n][ks], acc[m][n]);
    __builtin_amdgcn_s_setprio(0);

    // stage next-B mid-tile
    if (more) {
      if (!BF32) {
        #pragma unroll
        for (int i = 0; i < 4; ++i) {
          int c = i * 4 + wave;
          GLDS(Bb + (size_t)(n0 + c * 8 + srow8) * K + kb + scol, &Bs[buf ^ 1][c * 512]);
        }
      } else {
        #pragma unroll
        for (int it = 0; it < 4; ++it) {
          int idx = it * 256 + tid;
          int row = idx >> 3, p = idx & 7;
          int gc = (p - row) & 7;
          const float* src = Bf + (size_t)(n0 + row) * K + kb + gc * 8;
          float4 v0 = *(const float4*)src, v1 = *(const float4*)(src + 4);
          union { bf16x8 v; u16 s[8]; } u;
          u.s[0]=f2bf(v0.x); u.s[1]=f2bf(v0.y); u.s[2]=f2bf(v0.z); u.s[3]=f2bf(v0.w);
          u.s[4]=f2bf(v1.x); u.s[5]=f2bf(v1.y); u.s[6]=f2bf(v1.z); u.s[7]=f2bf(v1.w);
          *(bf16x8*)&Bs[buf ^ 1][row * 64 + p * 8] = u.v;
        }
      }
    }

    __builtin_amdgcn_s_setprio(1);
    #pragma unroll
    for (int n = 0; n < 4; ++n)
      #pragma unroll
      for (int ks = 0; ks < 2; ++ks)
        acc[2][n] = MFMA(af[2][ks], bfv[n][ks], acc[2][n]);
    __builtin_amdgcn_s_setprio(0);

    LGKM0;             // all this tile's LDS reads (and BF32 ds_writes) retired
    SCHEDB;
    SBAR;              // WAR publish: buffers may now be overwritten by next tile
    CFENCE; SCHEDB;

    // register-only tail: no LDS access after barB
    __builtin_amdgcn_s_setprio(1);
    #pragma unroll
    for (int n = 0; n < 4; ++n)
      #pragma unroll
      for (int ks = 0; ks < 2; ++ks)
        acc[3][n] = MFMA(af[3][ks], bfv[n][ks], acc[3][n]);
    __builtin_amdgcn_s_setprio(0);
  }

  int r0 = gp * 4;
  #pragma unroll
  for (int m = 0; m < 4; ++m) {
    #pragma unroll
    for (int n = 0; n < 4; ++n) {
      int col = n0 + wc * 64 + n * 16 + cl;
      #pragma unroll
      for (int j = 0; j < 4; ++j) {
        int row = m0 + wr * 64 + m * 16 + r0 + j;
        float v = acc[m][n][j];
        if (EPI == 1) v += R[(size_t)row * ldc + col];
        if (EPI == 2) v = fmaxf(v, 0.f);
        if (WF32) {
          if (NT) __builtin_nontemporal_store(v, &C[(size_t)row * ldc + col]);
          else C[(size_t)row * ldc + col] = v;
        }
        if (WB16) Cb[(size_t)row * ldc + col] = f2bf(v);
      }
    }
  }
}

// ======================================================================
// 256x256 GEMM, 8 waves (2Mx4N), 128KB dbuf LDS, counted-vmcnt dual-barrier loop.
template<int EPI, bool WF32, bool WB16, bool SWZ, bool NT = false>
__global__ __launch_bounds__(512) void gemm256(
    const u16* __restrict__ A, const u16* __restrict__ B,
    float* __restrict__ C, u16* __restrict__ Cb,
    const float* __restrict__ R, int K, int ldc)
{
  __shared__ u16 As[2][256 * 64];
  __shared__ u16 Bs[2][256 * 64];
  int tid = threadIdx.x;
  int lane = tid & 63, wave = tid >> 6;
  int wr = wave >> 2, wc = wave & 3;
  int cl = lane & 15, gp = (lane >> 4) & 3;

  int bx = blockIdx.x, by = blockIdx.y;
  if (SWZ) {
    int nwg = gridDim.x * gridDim.y;
    int flat = by * gridDim.x + bx;
    int cpx = nwg >> 3;
    int swz = (flat & 7) * cpx + (flat >> 3);
    bx = swz % gridDim.x; by = swz / gridDim.x;
  }
  int m0 = bx * 256, n0 = by * 256;

  int srow8 = lane >> 3;
  int scol = (((lane & 7) - srow8) & 7) * 8;
  int pos0 = ((gp + cl) & 7) * 8;
  int pos1 = ((gp + cl + 4) & 7) * 8;

  f32x4 acc[8][4] = {};
  int nk = K >> 6;

  // prologue: tile 0 (A then B — issue order matters for vmcnt math)
  #pragma unroll
  for (int i = 0; i < 4; ++i) {
    int c = i * 8 + wave;
    GLDS(A + (size_t)(m0 + c * 8 + srow8) * K + scol, &As[0][c * 512]);
  }
  #pragma unroll
  for (int i = 0; i < 4; ++i) {
    int c = i * 8 + wave;
    GLDS(B + (size_t)(n0 + c * 8 + srow8) * K + scol, &Bs[0][c * 512]);
  }

  for (int kt = 0; kt < nk; ++kt) {
    int buf = kt & 1;
    int kb = (kt + 1) << 6;
    bool more = kt + 1 < nk;

    if (more) {
      #pragma unroll
      for (int i = 0; i < 4; ++i) {
        int c = i * 8 + wave;
        GLDS(A + (size_t)(m0 + c * 8 + srow8) * K + kb + scol, &As[buf ^ 1][c * 512]);
      }
      VMCNT4;          // retire this tile's 8 loads; keep 4 next-A in flight
    } else {
      VMCNT0;
    }
    SCHEDB;
    SBAR;              // publish tile t
    CFENCE; SCHEDB;

    bf16x8 af0[4][2], af1[4][2], bf0[2][2], bf1[2][2];
    #pragma unroll
    for (int n = 0; n < 2; ++n) {
      int r = (wc * 64 + n * 16 + cl) * 64;
      bf0[n][0] = *(const bf16x8*)&Bs[buf][r + pos0];
      bf0[n][1] = *(const bf16x8*)&Bs[buf][r + pos1];
    }
    #pragma unroll
    for (int m = 0; m < 4; ++m) {
      int r = (wr * 128 + m * 16 + cl) * 64;
      af0[m][0] = *(const bf16x8*)&As[buf][r + pos0];
      af0[m][1] = *(const bf16x8*)&As[buf][r + pos1];
    }
    #pragma unroll
    for (int n = 0; n < 2; ++n) {
      int r = (wc * 64 + (n + 2) * 16 + cl) * 64;
      bf1[n][0] = *(const bf16x8*)&Bs[buf][r + pos0];
      bf1[n][1] = *(const bf16x8*)&Bs[buf][r + pos1];
    }
    #pragma unroll
    for (int m = 0; m < 4; ++m) {
      int r = (wr * 128 + (m + 4) * 16 + cl) * 64;
      af1[m][0] = *(const bf16x8*)&As[buf][r + pos0];
      af1[m][1] = *(const bf16x8*)&As[buf][r + pos1];
    }

    __builtin_amdgcn_s_setprio(1);
    #pragma unroll
    for (int m = 0; m < 4; ++m)
      #pragma unroll
      for (int n = 0; n < 2; ++n)
        #pragma unroll
        for (int ks = 0; ks < 2; ++ks)
          acc[m][n] = MFMA(af0[m][ks], bf0[n][ks], acc[m][n]);
    __builtin_amdgcn_s_setprio(0);

    if (more) {
      #pragma unroll
      for (int i = 0; i < 4; ++i) {
        int c = i * 8 + wave;
        GLDS(B + (size_t)(n0 + c * 8 + srow8) * K + kb + scol, &Bs[buf ^ 1][c * 512]);
      }
    }

    __builtin_amdgcn_s_setprio(1);
    #pragma unroll
    for (int m = 0; m < 4; ++m)
      #pragma unroll
      for (int n = 0; n < 2; ++n)
        #pragma unroll
        for (int ks = 0; ks < 2; ++ks)
          acc[m][n + 2] = MFMA(af0[m][ks], bf1[n][ks], acc[m][n + 2]);
    __builtin_amdgcn_s_setprio(0);

    LGKM0;             // all LDS reads of tile t retired
    SCHEDB;
    SBAR;              // WAR publish
    CFENCE; SCHEDB;

    // register-only tail (32 MFMA), overlaps other waves' staging of t+1
    __builtin_amdgcn_s_setprio(1);
    #pragma unroll
    for (int m = 0; m < 4; ++m)
      #pragma unroll
      for (int n = 0; n < 2; ++n)
        #pragma unroll
        for (int ks = 0; ks < 2; ++ks)
          acc[m + 4][n] = MFMA(af1[m][ks], bf0[n][ks], acc[m + 4][n]);
    #pragma unroll
    for (int m = 0; m < 4; ++m)
      #pragma unroll
      for (int n = 0; n < 2; ++n)
        #pragma unroll
        for (int ks = 0; ks < 2; ++ks)
          acc[m + 4][n + 2] = MFMA(af1[m][ks], bf1[n][ks], acc[m + 4][n + 2]);
    __builtin_amdgcn_s_setprio(0);
  }

  int r0 = gp * 4;
  #pragma unroll
  for (int m = 0; m < 8; ++m) {
    #pragma unroll
    for (int n = 0; n < 4; ++n) {
      int col = n0 + wc * 64 + n * 16 + cl;
      #pragma unroll
      for (int j = 0; j < 4; ++j) {
        int row = m0 + wr * 128 + m * 16 + r0 + j;
        float v = acc[m][n][j];
        if (EPI == 1) v += R[(size_t)row * ldc + col];
        if (EPI == 2) v = fmaxf(v, 0.f);
        if (WF32) {
          if (NT) __builtin_nontemporal_store(v, &C[(size_t)row * ldc + col]);
          else C[(size_t)row * ldc + col] = v;
        }
        if (WB16) Cb[(size_t)row * ldc + col] = f2bf(v);
      }
    }
  }
}

// ---------------- fused causal attention (round-5 verified version)
#define LSTR 72
__global__ __launch_bounds__(256) void attn_kernel(const u16* __restrict__ qkv,
                                                   u16* __restrict__ outb) {
  __shared__ u16 Ksm[2][64 * 64];
  __shared__ u16 Vsm[2][64 * LSTR];
  __shared__ u16 Psm[64 * LSTR];
  int qb = blockIdx.x, h = blockIdx.y, b = blockIdx.z;
  int tid = threadIdx.x;
  int lane = tid & 63, wave = tid >> 6;
  int cl = lane & 15, gp = lane >> 4;
  int srow8 = lane >> 3;
  int gsrc = (((lane & 7) - srow8) & 7) * 8;

  const u16* base = qkv + (size_t)b * SEQLEN * (3 * HIDDEN);

  int qrow_a = qb * 64 + wave * 16 + cl;
  const u16* qp = base + (size_t)qrow_a * (3 * HIDDEN) + h * HDIM;
  bf16x8 qf0 = *(const bf16x8*)(qp + gp * 8);
  bf16x8 qf1 = *(const bf16x8*)(qp + 32 + gp * 8);

  ushort4 vr[4];

  auto stageK = [&](int t, int bb) {
    #pragma unroll
    for (int i = 0; i < 2; ++i) {
      int c = wave * 2 + i;
      int row = c * 8 + srow8;
      GLDS(base + (size_t)(t * 64 + row) * (3 * HIDDEN) + HIDDEN + h * HDIM + gsrc,
           &Ksm[bb][c * 512]);
    }
  };
  auto loadV = [&](int t) {
    #pragma unroll
    for (int it = 0; it < 4; ++it) {
      int idx = it * 256 + tid;
      int row = idx >> 4, c4 = (idx & 15) * 4;
      vr[it] = *(const ushort4*)(base + (size_t)(t * 64 + row) * (3 * HIDDEN) +
                                 2 * HIDDEN + h * HDIM + c4);
    }
  };
  auto writeV = [&](int bb) {
    #pragma unroll
    for (int it = 0; it < 4; ++it) {
      int idx = it * 256 + tid;
      int row = idx >> 4, c4 = (idx & 15) * 4;
      Vsm[bb][(c4 + 0) * LSTR + row] = vr[it].x;
      Vsm[bb][(c4 + 1) * LSTR + row] = vr[it].y;
      Vsm[bb][(c4 + 2) * LSTR + row] = vr[it].z;
      Vsm[bb][(c4 + 3) * LSTR + row] = vr[it].w;
    }
  };

  stageK(0, 0);
  loadV(0);
  writeV(0);
  __syncthreads();

  float mrow[4], lrow[4];
  f32x4 oacc[4] = {};
  #pragma unroll
  for (int j = 0; j < 4; ++j) { mrow[j] = -INFINITY; lrow[j] = 0.f; }

  for (int t = 0; t <= qb; ++t) {
    int buf = t & 1;
    bool more = t < qb;
    if (more) { stageK(t + 1, buf ^ 1); loadV(t + 1); }

    f32x4 sfr[4];
    __builtin_amdgcn_s_setprio(1);
    #pragma unroll
    for (int n = 0; n < 4; ++n) {
      f32x4 z = {};
      bf16x8 kf0 = *(const bf16x8*)&Ksm[buf][(n * 16 + cl) * 64 + ((gp + cl) & 7) * 8];
      bf16x8 kf1 = *(const bf16x8*)&Ksm[buf][(n * 16 + cl) * 64 + ((gp + cl + 4) & 7) * 8];
      z = MFMA(qf0, kf0, z);
      z = MFMA(qf1, kf1, z);
      sfr[n] = z;
    }
    __builtin_amdgcn_s_setprio(0);

    #pragma unroll
    for (int n = 0; n < 4; ++n)
      #pragma unroll
      for (int j = 0; j < 4; ++j) {
        int qg = qb * 64 + wave * 16 + gp * 4 + j;
        int kg = t * 64 + n * 16 + cl;
        float sv = sfr[n][j] * 0.03125f;
        sfr[n][j] = (kg <= qg) ? sv : -1e30f;
      }
    float so[4];
    #pragma unroll
    for (int j = 0; j < 4; ++j) {
      float tm = fmaxf(fmaxf(sfr[0][j], sfr[1][j]), fmaxf(sfr[2][j], sfr[3][j]));
      tm = fmaxf(tm, __shfl_xor(tm, 1));
      tm = fmaxf(tm, __shfl_xor(tm, 2));
      tm = fmaxf(tm, __shfl_xor(tm, 4));
      tm = fmaxf(tm, __shfl_xor(tm, 8));
      float mn = fmaxf(mrow[j], tm);
      so[j] = __expf(mrow[j] - mn);
      mrow[j] = mn;
      float ts = 0.f;
      #pragma unroll
      for (int n = 0; n < 4; ++n) {
        float p = __expf(sfr[n][j] - mn);
        sfr[n][j] = p;
        ts += p;
      }
      ts += __shfl_xor(ts, 1); ts += __shfl_xor(ts, 2);
      ts += __shfl_xor(ts, 4); ts += __shfl_xor(ts, 8);
      lrow[j] = lrow[j] * so[j] + ts;
    }
    #pragma unroll
    for (int n = 0; n < 4; ++n)
      #pragma unroll
      for (int j = 0; j < 4; ++j)
        oacc[n][j] *= so[j];

    if (more) writeV(buf ^ 1);

    #pragma unroll
    for (int n = 0; n < 4; ++n)
      #pragma unroll
      for (int j = 0; j < 4; ++j)
        Psm[(wave * 16 + gp * 4 + j) * LSTR + n * 16 + cl] = f2bf(sfr[n][j]);
    __builtin_amdgcn_sched_barrier(0);

    bf16x8 pa0 = *(const bf16x8*)&Psm[(wave * 16 + cl) * LSTR + gp * 8];
    bf16x8 pa1 = *(const bf16x8*)&Psm[(wave * 16 + cl) * LSTR + 32 + gp * 8];
    __builtin_amdgcn_s_setprio(1);
    #pragma unroll
    for (int n = 0; n < 4; ++n) {
      bf16x8 vb0 = *(const bf16x8*)&Vsm[buf][(n * 16 + cl) * LSTR + gp * 8];
      bf16x8 vb1 = *(const bf16x8*)&Vsm[buf][(n * 16 + cl) * LSTR + 32 + gp * 8];
      oacc[n] = MFMA(pa0, vb0, oacc[n]);
      oacc[n] = MFMA(pa1, vb1, oacc[n]);
    }
    __builtin_amdgcn_s_setprio(0);

    __syncthreads();
  }

  #pragma unroll
  for (int n = 0; n < 4; ++n)
    #pragma unroll
    for (int j = 0; j < 4; ++j) {
      int qg = qb * 64 + wave * 16 + gp * 4 + j;
      int d = n * 16 + cl;
      outb[(size_t)(b * SEQLEN + qg) * HIDDEN + h * HDIM + d] = f2bf(oacc[n][j] / lrow[j]);
    }
}

extern "C" void kernel_launch(void* const* d_in, const int* in_sizes, int n_in,
                              void* d_out, int out_size, void* d_ws, size_t ws_size,
                              hipStream_t stream) {
  const int*   ids    = (const int*)d_in[0];
  const float* W_word = (const float*)d_in[1];
  const float* W_pos  = (const float*)d_in[2];
  const float* Wq     = (const float*)d_in[3];
  const float* Wk     = (const float*)d_in[4];
  const float* Wv     = (const float*)d_in[5];
  const float* Wo     = (const float*)d_in[6];
  const float* W1     = (const float*)d_in[7];
  const float* W2     = (const float*)d_in[8];
  const float* W_eh   = (const float*)d_in[9];
  const float* W_he   = (const float*)d_in[10];
  const float* W_lm   = (const float*)d_in[11];
  float* out = (float*)d_out;
  char*  ob  = (char*)d_out;
  char*  wb  = (char*)d_ws;

  const size_t MB = 1024 * 1024;
  float* h1    = (float*)(ob + 0 * MB);
  float* h2    = (float*)(ob + 16 * MB);
  u16*   h0b   = (u16*)(ob + 32 * MB);
  u16*   h1b   = (u16*)(ob + 36 * MB);
  u16*   qkvb  = (u16*)(ob + 44 * MB);
  u16*   attnb = (u16*)(ob + 68 * MB);
  u16*   h2b   = (u16*)(ob + 76 * MB);
  u16*   xb    = (u16*)(ob + 84 * MB);
  u16*   h3b   = (u16*)(ob + 116 * MB);
  u16*   Wqkv_b= (u16*)(ob + 124 * MB);
  u16*   Wo_b  = (u16*)(ob + 130 * MB);
  u16*   W1_b  = (u16*)(ob + 132 * MB);
  u16*   W2_b  = (u16*)(ob + 140 * MB);
  u16*   Weh_b = (u16*)(ob + 148 * MB);
  u16*   Whe_b = (u16*)(ob + 149 * MB);
  u16*   he_b  = (u16*)(wb + 0);
  u16*   Wlm_b = (u16*)(wb + 4 * MB);
  bool big_ws = ws_size >= 36 * MB;

  Cvt8 cc;
  cc.src[0] = Wq;  cc.dst[0] = Wqkv_b + 0 * 1024 * 1024;
  cc.src[1] = Wk;  cc.dst[1] = Wqkv_b + 1 * 1024 * 1024;
  cc.src[2] = Wv;  cc.dst[2] = Wqkv_b + 2 * 1024 * 1024;
  cc.src[3] = Wo;  cc.dst[3] = Wo_b;
  cc.src[4] = W1;  cc.dst[4] = W1_b;
  cc.src[5] = W2;  cc.dst[5] = W2_b;
  cc.src[6] = W_eh; cc.dst[6] = Weh_b;
  cc.src[7] = W_he; cc.dst[7] = Whe_b;
  cvt8_kernel<<<dim3(13312), 256, 0, stream>>>(cc);
  if (big_ws)
    cvt_kernel<<<dim3(16000), 256, 0, stream>>>(W_lm, Wlm_b);

  embed_kernel<<<dim3(ROWS), 128, 0, stream>>>(ids, W_word, W_pos, h0b);

  // h1 = h0 @ W_eh.T
  gemm128<0, true, true, false, false><<<dim3(32, 8), 256, 0, stream>>>(
      h0b, Weh_b, nullptr, h1, h1b, nullptr, 512, HIDDEN);
  // qkv = h1 @ Wqkv.T
  gemm128<0, false, true, false, false><<<dim3(32, 24), 256, 0, stream>>>(
      h1b, Wqkv_b, nullptr, nullptr, qkvb, nullptr, 1024, 3 * HIDDEN);
  // attention
  attn_kernel<<<dim3(16, 16, 4), 256, 0, stream>>>(qkvb, attnb);
  // h2 = h1 + attn @ Wo.T
  gemm128<1, true, true, false, false><<<dim3(32, 8), 256, 0, stream>>>(
      attnb, Wo_b, nullptr, h2, h2b, h1, 1024, HIDDEN);
  // x = relu(h2 @ W1.T)
  gemm256<2, false, true, false><<<dim3(16, 16), 512, 0, stream>>>(
      h2b, W1_b, nullptr, xb, nullptr, 1024, 4 * HIDDEN);
  // h3 = h2 + x @ W2.T
  gemm128<1, false, true, false, false><<<dim3(32, 8), 256, 0, stream>>>(
      xb, W2_b, nullptr, nullptr, h3b, h2, 4096, HIDDEN);
  // he = h3 @ W_he.T
  gemm128<0, false, true, false, false><<<dim3(32, 4), 256, 0, stream>>>(
      h3b, Whe_b, nullptr, nullptr, he_b, nullptr, 1024, EMBED);
  // logits = he @ W_lm.T  (nontemporal f32 stores)
  if (big_ws)
    gemm256<0, true, false, true, true><<<dim3(16, 125), 512, 0, stream>>>(
        he_b, Wlm_b, out, nullptr, nullptr, 512, VOCAB);
  else
    gemm128<0, true, false, true, true, true><<<dim3(32, 250), 256, 0, stream>>>(
        he_b, nullptr, W_lm, out, nullptr, nullptr, 512, VOCAB);
}

// Round 8
// 495.334 us; speedup vs baseline: 2.7521x; 1.0970x over previous
//
#include <hip/hip_runtime.h>
#include <hip/hip_bf16.h>

#define HIDDEN 1024
#define NHEAD 16
#define HDIM 64
#define VOCAB 32000
#define SEQLEN 1024
#define EMBED 512
#define BATCH 4
#define ROWS (BATCH*SEQLEN)   // 4096

typedef __bf16 bf16x8 __attribute__((ext_vector_type(8)));
typedef float f32x4 __attribute__((ext_vector_type(4)));
typedef unsigned short u16;

#define MFMA(a_, b_, c_) __builtin_amdgcn_mfma_f32_16x16x32_bf16(a_, b_, c_, 0, 0, 0)

#define VMCNT4 asm volatile("s_waitcnt vmcnt(4)" ::: "memory")
#define VMCNT0 asm volatile("s_waitcnt vmcnt(0)" ::: "memory")
#define LGKM0  asm volatile("s_waitcnt lgkmcnt(0)" ::: "memory")
#define CFENCE asm volatile("" ::: "memory")
#define SBAR   __builtin_amdgcn_s_barrier()
#define SCHEDB __builtin_amdgcn_sched_barrier(0)

__device__ __forceinline__ u16 f2bf(float f) {
  unsigned u = __builtin_bit_cast(unsigned, f);
  u = u + 0x7FFFu + ((u >> 16) & 1u);
  return (u16)(u >> 16);
}

// async global->LDS, 16B/lane; LDS dest = wave-uniform base + lane*16
#define GLDS(g_, l_) __builtin_amdgcn_global_load_lds( \
    (const __attribute__((address_space(1))) void*)(g_), \
    (__attribute__((address_space(3))) void*)(l_), 16, 0, 0)

// ---------------- fused prep: 8 small weight cvts + W_lm cvt + embedding
struct Prep {
  const float* src[8]; u16* dst[8];
  const float* wlm; u16* wlm_dst;          // wlm_dst may be null
  const int* ids; const float* wword; const float* wpos; u16* h0b;
};
__global__ void prep_kernel(Prep pp) {
  int b = blockIdx.x;
  if (b < 13312) {                          // 8 small weights
    int seg, off;
    if (b < 4096)        { seg = b >> 10; off = b & 1023; }
    else if (b < 8192)   { seg = 4; off = b - 4096; }
    else if (b < 12288)  { seg = 5; off = b - 8192; }
    else if (b < 12800)  { seg = 6; off = b - 12288; }
    else                 { seg = 7; off = b - 12800; }
    size_t i = ((size_t)off * 256 + threadIdx.x) * 4;
    float4 v = *(const float4*)(pp.src[seg] + i);
    unsigned a = f2bf(v.x) | ((unsigned)f2bf(v.y) << 16);
    unsigned d = f2bf(v.z) | ((unsigned)f2bf(v.w) << 16);
    *(uint2*)(pp.dst[seg] + i) = make_uint2(a, d);
  } else if (b < 29312) {                   // W_lm (32000*512 = 16000 blocks)
    if (!pp.wlm_dst) return;
    int off = b - 13312;
    size_t i = ((size_t)off * 256 + threadIdx.x) * 4;
    float4 v = *(const float4*)(pp.wlm + i);
    unsigned a = f2bf(v.x) | ((unsigned)f2bf(v.y) << 16);
    unsigned d = f2bf(v.z) | ((unsigned)f2bf(v.w) << 16);
    *(uint2*)(pp.wlm_dst + i) = make_uint2(a, d);
  } else {                                  // embedding: 2048 blocks, 2 rows each
    int off = b - 29312;
    int row = off * 2 + (threadIdx.x >> 7);
    int e = (threadIdx.x & 127) * 4;
    int s = row & (SEQLEN - 1);
    int id = pp.ids[row];
    float4 a = *(const float4*)(pp.wword + (size_t)id * EMBED + e);
    float4 c = *(const float4*)(pp.wpos + (size_t)s * EMBED + e);
    unsigned lo = f2bf(a.x + c.x) | ((unsigned)f2bf(a.y + c.y) << 16);
    unsigned hi = f2bf(a.z + c.z) | ((unsigned)f2bf(a.w + c.w) << 16);
    *(uint2*)(pp.h0b + (size_t)row * EMBED + e) = make_uint2(lo, hi);
  }
}

// ======================================================================
// 128x128 GEMM, 4 waves, dbuf LDS, rotation-swizzled, counted-vmcnt dual-barrier.
template<int EPI, bool WF32, bool WB16, bool BF32, bool SWZ, bool NT = false>
__global__ __launch_bounds__(256, 2) void gemm128(
    const u16* __restrict__ A, const u16* __restrict__ Bb,
    const float* __restrict__ Bf,
    float* __restrict__ C, u16* __restrict__ Cb,
    const float* __restrict__ R, int K, int ldc)
{
  __shared__ u16 As[2][128 * 64];
  __shared__ u16 Bs[2][128 * 64];
  int tid = threadIdx.x;
  int lane = tid & 63, wave = tid >> 6;
  int wr = wave >> 1, wc = wave & 1;
  int cl = lane & 15, gp = (lane >> 4) & 3;

  int bx = blockIdx.x, by = blockIdx.y;
  if (SWZ) {
    int nwg = gridDim.x * gridDim.y;
    int flat = by * gridDim.x + bx;
    int cpx = nwg >> 3;
    int swz = (flat & 7) * cpx + (flat >> 3);
    bx = swz % gridDim.x; by = swz / gridDim.x;
  }
  int m0 = bx * 128, n0 = by * 128;

  int srow8 = lane >> 3;
  int scol = (((lane & 7) - srow8) & 7) * 8;
  int pos0 = ((gp + cl) & 7) * 8;
  int pos1 = ((gp + cl + 4) & 7) * 8;

  f32x4 acc[4][4] = {};
  int nk = K >> 6;

  #pragma unroll
  for (int i = 0; i < 4; ++i) {
    int c = i * 4 + wave;
    GLDS(A + (size_t)(m0 + c * 8 + srow8) * K + scol, &As[0][c * 512]);
  }
  if (!BF32) {
    #pragma unroll
    for (int i = 0; i < 4; ++i) {
      int c = i * 4 + wave;
      GLDS(Bb + (size_t)(n0 + c * 8 + srow8) * K + scol, &Bs[0][c * 512]);
    }
  } else {
    #pragma unroll
    for (int it = 0; it < 4; ++it) {
      int idx = it * 256 + tid;
      int row = idx >> 3, p = idx & 7;
      int gc = (p - row) & 7;
      const float* src = Bf + (size_t)(n0 + row) * K + gc * 8;
      float4 v0 = *(const float4*)src, v1 = *(const float4*)(src + 4);
      union { bf16x8 v; u16 s[8]; } u;
      u.s[0]=f2bf(v0.x); u.s[1]=f2bf(v0.y); u.s[2]=f2bf(v0.z); u.s[3]=f2bf(v0.w);
      u.s[4]=f2bf(v1.x); u.s[5]=f2bf(v1.y); u.s[6]=f2bf(v1.z); u.s[7]=f2bf(v1.w);
      *(bf16x8*)&Bs[0][row * 64 + p * 8] = u.v;
    }
  }

  for (int kt = 0; kt < nk; ++kt) {
    int buf = kt & 1;
    int kb = (kt + 1) << 6;
    bool more = kt + 1 < nk;

    if (more) {
      #pragma unroll
      for (int i = 0; i < 4; ++i) {
        int c = i * 4 + wave;
        GLDS(A + (size_t)(m0 + c * 8 + srow8) * K + kb + scol, &As[buf ^ 1][c * 512]);
      }
    }
    if (BF32) { VMCNT0; } else if (more) { VMCNT4; } else { VMCNT0; }
    SCHEDB;
    SBAR;
    CFENCE; SCHEDB;

    bf16x8 af[4][2], bfv[4][2];
    #pragma unroll
    for (int n = 0; n < 4; ++n) {
      int r = (wc * 64 + n * 16 + cl) * 64;
      bfv[n][0] = *(const bf16x8*)&Bs[buf][r + pos0];
      bfv[n][1] = *(const bf16x8*)&Bs[buf][r + pos1];
    }
    #pragma unroll
    for (int m = 0; m < 4; ++m) {
      int r = (wr * 64 + m * 16 + cl) * 64;
      af[m][0] = *(const bf16x8*)&As[buf][r + pos0];
      af[m][1] = *(const bf16x8*)&As[buf][r + pos1];
    }

    __builtin_amdgcn_s_setprio(1);
    #pragma unroll
    for (int m = 0; m < 2; ++m)
      #pragma unroll
      for (int n = 0; n < 4; ++n)
        #pragma unroll
        for (int ks = 0; ks < 2; ++ks)
          acc[m][n] = MFMA(af[m][ks], bfv[n][ks], acc[m][n]);
    __builtin_amdgcn_s_setprio(0);

    if (more) {
      if (!BF32) {
        #pragma unroll
        for (int i = 0; i < 4; ++i) {
          int c = i * 4 + wave;
          GLDS(Bb + (size_t)(n0 + c * 8 + srow8) * K + kb + scol, &Bs[buf ^ 1][c * 512]);
        }
      } else {
        #pragma unroll
        for (int it = 0; it < 4; ++it) {
          int idx = it * 256 + tid;
          int row = idx >> 3, p = idx & 7;
          int gc = (p - row) & 7;
          const float* src = Bf + (size_t)(n0 + row) * K + kb + gc * 8;
          float4 v0 = *(const float4*)src, v1 = *(const float4*)(src + 4);
          union { bf16x8 v; u16 s[8]; } u;
          u.s[0]=f2bf(v0.x); u.s[1]=f2bf(v0.y); u.s[2]=f2bf(v0.z); u.s[3]=f2bf(v0.w);
          u.s[4]=f2bf(v1.x); u.s[5]=f2bf(v1.y); u.s[6]=f2bf(v1.z); u.s[7]=f2bf(v1.w);
          *(bf16x8*)&Bs[buf ^ 1][row * 64 + p * 8] = u.v;
        }
      }
    }

    __builtin_amdgcn_s_setprio(1);
    #pragma unroll
    for (int n = 0; n < 4; ++n)
      #pragma unroll
      for (int ks = 0; ks < 2; ++ks)
        acc[2][n] = MFMA(af[2][ks], bfv[n][ks], acc[2][n]);
    __builtin_amdgcn_s_setprio(0);

    LGKM0;
    SCHEDB;
    SBAR;
    CFENCE; SCHEDB;

    __builtin_amdgcn_s_setprio(1);
    #pragma unroll
    for (int n = 0; n < 4; ++n)
      #pragma unroll
      for (int ks = 0; ks < 2; ++ks)
        acc[3][n] = MFMA(af[3][ks], bfv[n][ks], acc[3][n]);
    __builtin_amdgcn_s_setprio(0);
  }

  int r0 = gp * 4;
  #pragma unroll
  for (int m = 0; m < 4; ++m) {
    #pragma unroll
    for (int n = 0; n < 4; ++n) {
      int col = n0 + wc * 64 + n * 16 + cl;
      #pragma unroll
      for (int j = 0; j < 4; ++j) {
        int row = m0 + wr * 64 + m * 16 + r0 + j;
        float v = acc[m][n][j];
        if (EPI == 1) v += R[(size_t)row * ldc + col];
        if (EPI == 2) v = fmaxf(v, 0.f);
        if (WF32) {
          if (NT) __builtin_nontemporal_store(v, &C[(size_t)row * ldc + col]);
          else C[(size_t)row * ldc + col] = v;
        }
        if (WB16) Cb[(size_t)row * ldc + col] = f2bf(v);
      }
    }
  }
}

// ======================================================================
// 256x256 GEMM, 8 waves (2Mx4N), 128KB dbuf LDS, counted-vmcnt dual-barrier.
// WF32 && !WB16 path uses LDS-transposed coalesced f32x4 stores.
template<int EPI, bool WF32, bool WB16, bool SWZ, bool NT = false>
__global__ __launch_bounds__(512) void gemm256(
    const u16* __restrict__ A, const u16* __restrict__ B,
    float* __restrict__ C, u16* __restrict__ Cb,
    const float* __restrict__ R, int K, int ldc)
{
  __shared__ __align__(16) u16 smem[4][256 * 64];   // [0..1]=As, [2..3]=Bs; epilogue reuse
  int tid = threadIdx.x;
  int lane = tid & 63, wave = tid >> 6;
  int wr = wave >> 2, wc = wave & 3;
  int cl = lane & 15, gp = (lane >> 4) & 3;

  int bx = blockIdx.x, by = blockIdx.y;
  if (SWZ) {
    int nwg = gridDim.x * gridDim.y;
    int flat = by * gridDim.x + bx;
    int cpx = nwg >> 3;
    int swz = (flat & 7) * cpx + (flat >> 3);
    bx = swz % gridDim.x; by = swz / gridDim.x;
  }
  int m0 = bx * 256, n0 = by * 256;

  int srow8 = lane >> 3;
  int scol = (((lane & 7) - srow8) & 7) * 8;
  int pos0 = ((gp + cl) & 7) * 8;
  int pos1 = ((gp + cl + 4) & 7) * 8;

  f32x4 acc[8][4] = {};
  int nk = K >> 6;

  #pragma unroll
  for (int i = 0; i < 4; ++i) {
    int c = i * 8 + wave;
    GLDS(A + (size_t)(m0 + c * 8 + srow8) * K + scol, &smem[0][c * 512]);
  }
  #pragma unroll
  for (int i = 0; i < 4; ++i) {
    int c = i * 8 + wave;
    GLDS(B + (size_t)(n0 + c * 8 + srow8) * K + scol, &smem[2][c * 512]);
  }

  for (int kt = 0; kt < nk; ++kt) {
    int buf = kt & 1;
    int kb = (kt + 1) << 6;
    bool more = kt + 1 < nk;

    if (more) {
      #pragma unroll
      for (int i = 0; i < 4; ++i) {
        int c = i * 8 + wave;
        GLDS(A + (size_t)(m0 + c * 8 + srow8) * K + kb + scol, &smem[buf ^ 1][c * 512]);
      }
      VMCNT4;
    } else {
      VMCNT0;
    }
    SCHEDB;
    SBAR;
    CFENCE; SCHEDB;

    bf16x8 af0[4][2], af1[4][2], bf0[2][2], bf1[2][2];
    #pragma unroll
    for (int n = 0; n < 2; ++n) {
      int r = (wc * 64 + n * 16 + cl) * 64;
      bf0[n][0] = *(const bf16x8*)&smem[2 + buf][r + pos0];
      bf0[n][1] = *(const bf16x8*)&smem[2 + buf][r + pos1];
    }
    #pragma unroll
    for (int m = 0; m < 4; ++m) {
      int r = (wr * 128 + m * 16 + cl) * 64;
      af0[m][0] = *(const bf16x8*)&smem[buf][r + pos0];
      af0[m][1] = *(const bf16x8*)&smem[buf][r + pos1];
    }
    #pragma unroll
    for (int n = 0; n < 2; ++n) {
      int r = (wc * 64 + (n + 2) * 16 + cl) * 64;
      bf1[n][0] = *(const bf16x8*)&smem[2 + buf][r + pos0];
      bf1[n][1] = *(const bf16x8*)&smem[2 + buf][r + pos1];
    }
    #pragma unroll
    for (int m = 0; m < 4; ++m) {
      int r = (wr * 128 + (m + 4) * 16 + cl) * 64;
      af1[m][0] = *(const bf16x8*)&smem[buf][r + pos0];
      af1[m][1] = *(const bf16x8*)&smem[buf][r + pos1];
    }

    __builtin_amdgcn_s_setprio(1);
    #pragma unroll
    for (int m = 0; m < 4; ++m)
      #pragma unroll
      for (int n = 0; n < 2; ++n)
        #pragma unroll
        for (int ks = 0; ks < 2; ++ks)
          acc[m][n] = MFMA(af0[m][ks], bf0[n][ks], acc[m][n]);
    __builtin_amdgcn_s_setprio(0);

    if (more) {
      #pragma unroll
      for (int i = 0; i < 4; ++i) {
        int c = i * 8 + wave;
        GLDS(B + (size_t)(n0 + c * 8 + srow8) * K + kb + scol, &smem[2 + (buf ^ 1)][c * 512]);
      }
    }

    __builtin_amdgcn_s_setprio(1);
    #pragma unroll
    for (int m = 0; m < 4; ++m)
      #pragma unroll
      for (int n = 0; n < 2; ++n)
        #pragma unroll
        for (int ks = 0; ks < 2; ++ks)
          acc[m][n + 2] = MFMA(af0[m][ks], bf1[n][ks], acc[m][n + 2]);
    __builtin_amdgcn_s_setprio(0);

    LGKM0;
    SCHEDB;
    SBAR;
    CFENCE; SCHEDB;

    __builtin_amdgcn_s_setprio(1);
    #pragma unroll
    for (int m = 0; m < 4; ++m)
      #pragma unroll
      for (int n = 0; n < 2; ++n)
        #pragma unroll
        for (int ks = 0; ks < 2; ++ks)
          acc[m + 4][n] = MFMA(af1[m][ks], bf0[n][ks], acc[m + 4][n]);
    #pragma unroll
    for (int m = 0; m < 4; ++m)
      #pragma unroll
      for (int n = 0; n < 2; ++n)
        #pragma unroll
        for (int ks = 0; ks < 2; ++ks)
          acc[m + 4][n + 2] = MFMA(af1[m][ks], bf1[n][ks], acc[m + 4][n + 2]);
    __builtin_amdgcn_s_setprio(0);
  }

  if (WF32 && !WB16) {
    // coalesced epilogue: stage 64-row groups in LDS (f32, stride 260), stream 1KB rows
    float* Cst = (float*)&smem[0][0];    // 64*260*4 = 66560 B of the 128KB
    __syncthreads();
    #pragma unroll
    for (int g = 0; g < 4; ++g) {
      if ((g >> 1) == wr) {
        #pragma unroll
        for (int k = 0; k < 4; ++k) {
          int ar = (g & 1) * 4 + k;
          int rl = ar * 16 + gp * 4 - (g & 1) * 64;   // 0..60 within group
          #pragma unroll
          for (int n = 0; n < 4; ++n) {
            int col = wc * 64 + n * 16 + cl;
            #pragma unroll
            for (int j = 0; j < 4; ++j)
              Cst[(rl + j) * 260 + col] = acc[ar][n][j];
          }
        }
      }
      __syncthreads();
      #pragma unroll
      for (int p = 0; p < 8; ++p) {
        int r = p * 8 + wave;               // 8 waves -> 8 rows per pass
        int c4 = lane * 4;                  // 64 lanes x 4 = 256 contiguous cols
        int grow = m0 + g * 64 + r;
        f32x4 v = *(f32x4*)&Cst[r * 260 + c4];
        if (EPI == 1) {
          f32x4 rv = *(const f32x4*)&R[(size_t)grow * ldc + n0 + c4];
          v = v + rv;
        }
        if (EPI == 2) {
          #pragma unroll
          for (int j = 0; j < 4; ++j) v[j] = fmaxf(v[j], 0.f);
        }
        if (NT) __builtin_nontemporal_store(v, (f32x4*)&C[(size_t)grow * ldc + n0 + c4]);
        else *(f32x4*)&C[(size_t)grow * ldc + n0 + c4] = v;
      }
      __syncthreads();
    }
  } else {
    int r0 = gp * 4;
    #pragma unroll
    for (int m = 0; m < 8; ++m) {
      #pragma unroll
      for (int n = 0; n < 4; ++n) {
        int col = n0 + wc * 64 + n * 16 + cl;
        #pragma unroll
        for (int j = 0; j < 4; ++j) {
          int row = m0 + wr * 128 + m * 16 + r0 + j;
          float v = acc[m][n][j];
          if (EPI == 1) v += R[(size_t)row * ldc + col];
          if (EPI == 2) v = fmaxf(v, 0.f);
          if (WF32) C[(size_t)row * ldc + col] = v;
          if (WB16) Cb[(size_t)row * ldc + col] = f2bf(v);
        }
      }
    }
  }
}

// ---------------- fused causal attention (round-5 verified version)
#define LSTR 72
__global__ __launch_bounds__(256) void attn_kernel(const u16* __restrict__ qkv,
                                                   u16* __restrict__ outb) {
  __shared__ u16 Ksm[2][64 * 64];
  __shared__ u16 Vsm[2][64 * LSTR];
  __shared__ u16 Psm[64 * LSTR];
  int qb = blockIdx.x, h = blockIdx.y, b = blockIdx.z;
  int tid = threadIdx.x;
  int lane = tid & 63, wave = tid >> 6;
  int cl = lane & 15, gp = lane >> 4;
  int srow8 = lane >> 3;
  int gsrc = (((lane & 7) - srow8) & 7) * 8;

  const u16* base = qkv + (size_t)b * SEQLEN * (3 * HIDDEN);

  int qrow_a = qb * 64 + wave * 16 + cl;
  const u16* qp = base + (size_t)qrow_a * (3 * HIDDEN) + h * HDIM;
  bf16x8 qf0 = *(const bf16x8*)(qp + gp * 8);
  bf16x8 qf1 = *(const bf16x8*)(qp + 32 + gp * 8);

  ushort4 vr[4];

  auto stageK = [&](int t, int bb) {
    #pragma unroll
    for (int i = 0; i < 2; ++i) {
      int c = wave * 2 + i;
      int row = c * 8 + srow8;
      GLDS(base + (size_t)(t * 64 + row) * (3 * HIDDEN) + HIDDEN + h * HDIM + gsrc,
           &Ksm[bb][c * 512]);
    }
  };
  auto loadV = [&](int t) {
    #pragma unroll
    for (int it = 0; it < 4; ++it) {
      int idx = it * 256 + tid;
      int row = idx >> 4, c4 = (idx & 15) * 4;
      vr[it] = *(const ushort4*)(base + (size_t)(t * 64 + row) * (3 * HIDDEN) +
                                 2 * HIDDEN + h * HDIM + c4);
    }
  };
  auto writeV = [&](int bb) {
    #pragma unroll
    for (int it = 0; it < 4; ++it) {
      int idx = it * 256 + tid;
      int row = idx >> 4, c4 = (idx & 15) * 4;
      Vsm[bb][(c4 + 0) * LSTR + row] = vr[it].x;
      Vsm[bb][(c4 + 1) * LSTR + row] = vr[it].y;
      Vsm[bb][(c4 + 2) * LSTR + row] = vr[it].z;
      Vsm[bb][(c4 + 3) * LSTR + row] = vr[it].w;
    }
  };

  stageK(0, 0);
  loadV(0);
  writeV(0);
  __syncthreads();

  float mrow[4], lrow[4];
  f32x4 oacc[4] = {};
  #pragma unroll
  for (int j = 0; j < 4; ++j) { mrow[j] = -INFINITY; lrow[j] = 0.f; }

  for (int t = 0; t <= qb; ++t) {
    int buf = t & 1;
    bool more = t < qb;
    if (more) { stageK(t + 1, buf ^ 1); loadV(t + 1); }

    f32x4 sfr[4];
    __builtin_amdgcn_s_setprio(1);
    #pragma unroll
    for (int n = 0; n < 4; ++n) {
      f32x4 z = {};
      bf16x8 kf0 = *(const bf16x8*)&Ksm[buf][(n * 16 + cl) * 64 + ((gp + cl) & 7) * 8];
      bf16x8 kf1 = *(const bf16x8*)&Ksm[buf][(n * 16 + cl) * 64 + ((gp + cl + 4) & 7) * 8];
      z = MFMA(qf0, kf0, z);
      z = MFMA(qf1, kf1, z);
      sfr[n] = z;
    }
    __builtin_amdgcn_s_setprio(0);

    #pragma unroll
    for (int n = 0; n < 4; ++n)
      #pragma unroll
      for (int j = 0; j < 4; ++j) {
        int qg = qb * 64 + wave * 16 + gp * 4 + j;
        int kg = t * 64 + n * 16 + cl;
        float sv = sfr[n][j] * 0.03125f;
        sfr[n][j] = (kg <= qg) ? sv : -1e30f;
      }
    float so[4];
    #pragma unroll
    for (int j = 0; j < 4; ++j) {
      float tm = fmaxf(fmaxf(sfr[0][j], sfr[1][j]), fmaxf(sfr[2][j], sfr[3][j]));
      tm = fmaxf(tm, __shfl_xor(tm, 1));
      tm = fmaxf(tm, __shfl_xor(tm, 2));
      tm = fmaxf(tm, __shfl_xor(tm, 4));
      tm = fmaxf(tm, __shfl_xor(tm, 8));
      float mn = fmaxf(mrow[j], tm);
      so[j] = __expf(mrow[j] - mn);
      mrow[j] = mn;
      float ts = 0.f;
      #pragma unroll
      for (int n = 0; n < 4; ++n) {
        float p = __expf(sfr[n][j] - mn);
        sfr[n][j] = p;
        ts += p;
      }
      ts += __shfl_xor(ts, 1); ts += __shfl_xor(ts, 2);
      ts += __shfl_xor(ts, 4); ts += __shfl_xor(ts, 8);
      lrow[j] = lrow[j] * so[j] + ts;
    }
    #pragma unroll
    for (int n = 0; n < 4; ++n)
      #pragma unroll
      for (int j = 0; j < 4; ++j)
        oacc[n][j] *= so[j];

    if (more) writeV(buf ^ 1);

    #pragma unroll
    for (int n = 0; n < 4; ++n)
      #pragma unroll
      for (int j = 0; j < 4; ++j)
        Psm[(wave * 16 + gp * 4 + j) * LSTR + n * 16 + cl] = f2bf(sfr[n][j]);
    __builtin_amdgcn_sched_barrier(0);

    bf16x8 pa0 = *(const bf16x8*)&Psm[(wave * 16 + cl) * LSTR + gp * 8];
    bf16x8 pa1 = *(const bf16x8*)&Psm[(wave * 16 + cl) * LSTR + 32 + gp * 8];
    __builtin_amdgcn_s_setprio(1);
    #pragma unroll
    for (int n = 0; n < 4; ++n) {
      bf16x8 vb0 = *(const bf16x8*)&Vsm[buf][(n * 16 + cl) * LSTR + gp * 8];
      bf16x8 vb1 = *(const bf16x8*)&Vsm[buf][(n * 16 + cl) * LSTR + 32 + gp * 8];
      oacc[n] = MFMA(pa0, vb0, oacc[n]);
      oacc[n] = MFMA(pa1, vb1, oacc[n]);
    }
    __builtin_amdgcn_s_setprio(0);

    __syncthreads();
  }

  #pragma unroll
  for (int n = 0; n < 4; ++n)
    #pragma unroll
    for (int j = 0; j < 4; ++j) {
      int qg = qb * 64 + wave * 16 + gp * 4 + j;
      int d = n * 16 + cl;
      outb[(size_t)(b * SEQLEN + qg) * HIDDEN + h * HDIM + d] = f2bf(oacc[n][j] / lrow[j]);
    }
}

extern "C" void kernel_launch(void* const* d_in, const int* in_sizes, int n_in,
                              void* d_out, int out_size, void* d_ws, size_t ws_size,
                              hipStream_t stream) {
  const int*   ids    = (const int*)d_in[0];
  const float* W_word = (const float*)d_in[1];
  const float* W_pos  = (const float*)d_in[2];
  const float* Wq     = (const float*)d_in[3];
  const float* Wk     = (const float*)d_in[4];
  const float* Wv     = (const float*)d_in[5];
  const float* Wo     = (const float*)d_in[6];
  const float* W1     = (const float*)d_in[7];
  const float* W2     = (const float*)d_in[8];
  const float* W_eh   = (const float*)d_in[9];
  const float* W_he   = (const float*)d_in[10];
  const float* W_lm   = (const float*)d_in[11];
  float* out = (float*)d_out;
  char*  ob  = (char*)d_out;
  char*  wb  = (char*)d_ws;

  const size_t MB = 1024 * 1024;
  float* h1    = (float*)(ob + 0 * MB);
  float* h2    = (float*)(ob + 16 * MB);
  u16*   h0b   = (u16*)(ob + 32 * MB);
  u16*   h1b   = (u16*)(ob + 36 * MB);
  u16*   qkvb  = (u16*)(ob + 44 * MB);
  u16*   attnb = (u16*)(ob + 68 * MB);
  u16*   h2b   = (u16*)(ob + 76 * MB);
  u16*   xb    = (u16*)(ob + 84 * MB);
  u16*   h3b   = (u16*)(ob + 116 * MB);
  u16*   Wqkv_b= (u16*)(ob + 124 * MB);
  u16*   Wo_b  = (u16*)(ob + 130 * MB);
  u16*   W1_b  = (u16*)(ob + 132 * MB);
  u16*   W2_b  = (u16*)(ob + 140 * MB);
  u16*   Weh_b = (u16*)(ob + 148 * MB);
  u16*   Whe_b = (u16*)(ob + 149 * MB);
  u16*   he_b  = (u16*)(wb + 0);
  u16*   Wlm_b = (u16*)(wb + 4 * MB);
  bool big_ws = ws_size >= 36 * MB;

  Prep pp;
  pp.src[0] = Wq;  pp.dst[0] = Wqkv_b + 0 * 1024 * 1024;
  pp.src[1] = Wk;  pp.dst[1] = Wqkv_b + 1 * 1024 * 1024;
  pp.src[2] = Wv;  pp.dst[2] = Wqkv_b + 2 * 1024 * 1024;
  pp.src[3] = Wo;  pp.dst[3] = Wo_b;
  pp.src[4] = W1;  pp.dst[4] = W1_b;
  pp.src[5] = W2;  pp.dst[5] = W2_b;
  pp.src[6] = W_eh; pp.dst[6] = Weh_b;
  pp.src[7] = W_he; pp.dst[7] = Whe_b;
  pp.wlm = W_lm; pp.wlm_dst = big_ws ? Wlm_b : nullptr;
  pp.ids = ids; pp.wword = W_word; pp.wpos = W_pos; pp.h0b = h0b;
  prep_kernel<<<dim3(31360), 256, 0, stream>>>(pp);

  // h1 = h0 @ W_eh.T
  gemm128<0, true, true, false, false><<<dim3(32, 8), 256, 0, stream>>>(
      h0b, Weh_b, nullptr, h1, h1b, nullptr, 512, HIDDEN);
  // qkv = h1 @ Wqkv.T
  gemm128<0, false, true, false, false><<<dim3(32, 24), 256, 0, stream>>>(
      h1b, Wqkv_b, nullptr, nullptr, qkvb, nullptr, 1024, 3 * HIDDEN);
  // attention
  attn_kernel<<<dim3(16, 16, 4), 256, 0, stream>>>(qkvb, attnb);
  // h2 = h1 + attn @ Wo.T
  gemm128<1, true, true, false, false><<<dim3(32, 8), 256, 0, stream>>>(
      attnb, Wo_b, nullptr, h2, h2b, h1, 1024, HIDDEN);
  // x = relu(h2 @ W1.T)
  gemm256<2, false, true, false><<<dim3(16, 16), 512, 0, stream>>>(
      h2b, W1_b, nullptr, xb, nullptr, 1024, 4 * HIDDEN);
  // h3 = h2 + x @ W2.T
  gemm128<1, false, true, false, false><<<dim3(32, 8), 256, 0, stream>>>(
      xb, W2_b, nullptr, nullptr, h3b, h2, 4096, HIDDEN);
  // he = h3 @ W_he.T
  gemm128<0, false, true, false, false><<<dim3(32, 4), 256, 0, stream>>>(
      h3b, Whe_b, nullptr, nullptr, he_b, nullptr, 1024, EMBED);
  // logits = he @ W_lm.T  (coalesced NT f32x4 stores)
  if (big_ws)
    gemm256<0, true, false, true, true><<<dim3(16, 125), 512, 0, stream>>>(
        he_b, Wlm_b, out, nullptr, nullptr, 512, VOCAB);
  else
    gemm128<0, true, false, true, true, true><<<dim3(32, 250), 256, 0, stream>>>(
        he_b, nullptr, W_lm, out, nullptr, nullptr, 512, VOCAB);
}